// Round 14
// baseline (110.113 us; speedup 1.0000x reference)
//
#include <hip/hip_runtime.h>

typedef __attribute__((ext_vector_type(8))) short bf16x8;
typedef __attribute__((ext_vector_type(4))) float f32x4;
typedef __attribute__((ext_vector_type(16))) float f32x16;

__device__ __forceinline__ ushort f2bf(float f) {
    union { float f; unsigned u; } x; x.f = f;
    unsigned r = x.u + 0x7fffu + ((x.u >> 16) & 1u);
    return (ushort)(r >> 16);
}

__device__ __forceinline__ void async16(const void* g, void* l) {
    __builtin_amdgcn_global_load_lds(
        (const __attribute__((address_space(1))) void*)g,
        (__attribute__((address_space(3))) void*)l, 16, 0, 0);
}

__device__ __forceinline__ f32x4 mfma16(bf16x8 a, bf16x8 b, f32x4 c) {
    return __builtin_amdgcn_mfma_f32_16x16x32_bf16(a, b, c, 0, 0, 0);
}
__device__ __forceinline__ f32x16 mfma32(bf16x8 a, bf16x8 b, f32x16 c) {
    return __builtin_amdgcn_mfma_f32_32x32x16_bf16(a, b, c, 0, 0, 0);
}

__device__ __forceinline__ f32x4 zero4() { f32x4 z = {0.f, 0.f, 0.f, 0.f}; return z; }

// cross-half (lane vs lane^32) reduce — VERIFIED shfl_xor form (R3-R5/R8/R9).
// NOTE: inline-asm v_permlane32_swap_b32 failed correctness in both operand
// orders (R6/R7, absmax ~4) — do not reintroduce.
__device__ __forceinline__ float xhalf_max(float v) {
    return fmaxf(v, __shfl_xor(v, 32));
}
__device__ __forceinline__ float xhalf_sum(float v) {
    return v + __shfl_xor(v, 32);
}

#define PIPE_BARRIER(cond_more)                                          \
    do {                                                                 \
        if (cond_more) asm volatile("s_waitcnt vmcnt(4)" ::: "memory");  \
        else           asm volatile("s_waitcnt vmcnt(0)" ::: "memory");  \
        asm volatile("s_waitcnt lgkmcnt(0)" ::: "memory");               \
        __builtin_amdgcn_sched_barrier(0);                               \
        __builtin_amdgcn_s_barrier();                                    \
        __builtin_amdgcn_sched_barrier(0);                               \
    } while (0)

#define END_BARRIER()                                                    \
    do {                                                                 \
        asm volatile("s_waitcnt lgkmcnt(0)" ::: "memory");               \
        __builtin_amdgcn_sched_barrier(0);                               \
        __builtin_amdgcn_s_barrier();                                    \
        __builtin_amdgcn_sched_barrier(0);                               \
    } while (0)

// -------- fused fp32 -> bf16 conversion for all 7 tensors, one launch --------
__global__ void cvt7_kernel(
    const float* __restrict__ s0, const float* __restrict__ s1, const float* __restrict__ s2,
    const float* __restrict__ s3, const float* __restrict__ s4, const float* __restrict__ s5,
    const float* __restrict__ s6,
    ushort* __restrict__ d0, ushort* __restrict__ d1, ushort* __restrict__ d2,
    ushort* __restrict__ d3, ushort* __restrict__ d4, ushort* __restrict__ d5,
    ushort* __restrict__ d6)
{
    int y = blockIdx.y;
    const float* s; ushort* d; int n4;
    if      (y == 0) { s = s0; d = d0; n4 = 1048576; }
    else if (y == 1) { s = s1; d = d1; n4 = 1048576; }
    else if (y == 2) { s = s2; d = d2; n4 = 1048576; }
    else if (y == 3) { s = s3; d = d3; n4 = 262144; }
    else if (y == 4) { s = s4; d = d4; n4 = 262144; }
    else if (y == 5) { s = s5; d = d5; n4 = 262144; }
    else             { s = s6; d = d6; n4 = 262144; }
    int i = blockIdx.x * 256 + threadIdx.x;
    if (i >= n4) return;
    float4 v = ((const float4*)s)[i];
    ushort4 o;
    o.x = f2bf(v.x); o.y = f2bf(v.y); o.z = f2bf(v.z); o.w = f2bf(v.w);
    ((ushort4*)d)[i] = o;
}

// -------- shared GEMM core: 128x128 tile, BK=32, 3-deep counted-vmcnt pipeline --------
template<bool SWAP>
__device__ __forceinline__ void gemm_core(
    const ushort* __restrict__ A, const ushort* __restrict__ W,
    char* smem, int bm, int bn, int tid, f32x4 acc[4][4])
{
    const int lane = tid & 63;
    const int wid  = tid >> 6;
    const int wr = wid >> 1, wc = wid & 1;
    const int l15 = lane & 15, g = lane >> 4;

    auto stage = [&](int kt) {
        char* As = smem + (kt % 3) * 16384;
        char* Bs = As + 8192;
        #pragma unroll
        for (int it = 0; it < 2; ++it) {
            int c = it * 256 + tid;
            int row = c >> 2, inner = c & 3;
            int srcoff = (inner ^ (row & 3)) * 16;
            async16((const char*)A + (size_t)(bm * 128 + row) * 2048 + kt * 64 + srcoff, As + c * 16);
            async16((const char*)W + (size_t)(bn * 128 + row) * 2048 + kt * 64 + srcoff, Bs + c * 16);
        }
    };

    stage(0);
    stage(1);

    for (int kt = 0; kt < 32; ++kt) {
        PIPE_BARRIER(kt < 31);
        if (kt < 30) stage(kt + 2);

        const char* As = smem + (kt % 3) * 16384;
        const char* Bs = As + 8192;
        bf16x8 af[4], bfr[4];
        #pragma unroll
        for (int mt = 0; mt < 4; ++mt) {
            int row = wr * 64 + mt * 16 + l15;
            af[mt] = *(const bf16x8*)(As + ((row * 64 + g * 16) ^ ((row & 3) << 4)));
        }
        #pragma unroll
        for (int nt = 0; nt < 4; ++nt) {
            int row = wc * 64 + nt * 16 + l15;
            bfr[nt] = *(const bf16x8*)(Bs + ((row * 64 + g * 16) ^ ((row & 3) << 4)));
        }
        __builtin_amdgcn_s_setprio(1);
        #pragma unroll
        for (int mt = 0; mt < 4; ++mt)
            #pragma unroll
            for (int nt = 0; nt < 4; ++nt) {
                if (SWAP) acc[mt][nt] = mfma16(bfr[nt], af[mt], acc[mt][nt]);
                else      acc[mt][nt] = mfma16(af[mt], bfr[nt], acc[mt][nt]);
            }
        __builtin_amdgcn_s_setprio(0);
    }
}

// -------- merged QKV projection: grid (96, 8), z = x%3 --------
// Q scaled by 0.125*log2(e) (exp2-domain softmax downstream).
// R14: coalesced epilogues via LDS bounce (16B stores, 128-512B runs).
__global__ __launch_bounds__(256, 2) void gemm_qkv(
    const ushort* __restrict__ Qb, const ushort* __restrict__ Kb, const ushort* __restrict__ Vb,
    const ushort* __restrict__ WQ, const ushort* __restrict__ WK, const ushort* __restrict__ WV,
    ushort* __restrict__ qhb, ushort* __restrict__ khb, ushort* __restrict__ vhT)
{
    __shared__ __align__(16) char smem[49152];
    const int tid = threadIdx.x;
    const int z  = blockIdx.x % 3;
    const int bm = blockIdx.x / 3;
    const int bn = blockIdx.y;
    const int lane = tid & 63;
    const int wid  = tid >> 6;
    const int wr = wid >> 1, wc = wid & 1;
    const int l15 = lane & 15, g = lane >> 4;

    const ushort* A  = (z == 0) ? Qb : (z == 1) ? Kb : Vb;
    const ushort* Wm = (z == 0) ? WQ : (z == 1) ? WK : WV;

    f32x4 acc[4][4];
    #pragma unroll
    for (int i = 0; i < 4; ++i)
        #pragma unroll
        for (int j = 0; j < 4; ++j) acc[i][j] = zero4();

    float* ep = (float*)smem;

    if (z == 2) {
        gemm_core<true>(A, Wm, smem, bm, bn, tid, acc);
        // D rows = W rows (d-model index n), cols = A rows (token m).
        // Bounce per m-half: ep[n 0..127][m 0..63] pitch 66, then 16B stores.
        #pragma unroll
        for (int h = 0; h < 2; ++h) {
            __syncthreads();
            if (wr == h) {
                #pragma unroll
                for (int mt = 0; mt < 4; ++mt)
                    #pragma unroll
                    for (int nt = 0; nt < 4; ++nt)
                        #pragma unroll
                        for (int j = 0; j < 4; ++j) {
                            int n_l = wc * 64 + nt * 16 + g * 4 + j;
                            int m_l = mt * 16 + l15;
                            ep[n_l * 66 + m_l] = acc[mt][nt][j];
                        }
            }
            __syncthreads();
            #pragma unroll
            for (int rr = 0; rr < 4; ++rr) {
                int n_l = rr * 32 + (tid >> 3);
                int mc  = (tid & 7) * 8;
                ushort u[8];
                #pragma unroll
                for (int e = 0; e < 8; ++e) u[e] = f2bf(ep[n_l * 66 + mc + e]);
                int n_g = bn * 128 + n_l;
                int hh = (n_g >> 6) & 15, d = n_g & 63;
                int m_g = bm * 128 + h * 64 + mc;
                int b = m_g >> 11, s = m_g & 2047;
                *(uint4*)&vhT[(((size_t)(b * 16 + hh)) * 64 + d) * 2048 + s] = *(const uint4*)u;
            }
        }
    } else {
        gemm_core<false>(A, Wm, smem, bm, bn, tid, acc);
        const float scale = (z == 0) ? 0.18033688011112042f : 1.0f;  // 0.125 * log2(e)
        ushort* outb = (z == 0) ? qhb : khb;
        // Bounce per m-half: ep[m 0..63][n 0..127] pitch 132, then 16B stores.
        #pragma unroll
        for (int h = 0; h < 2; ++h) {
            __syncthreads();
            if (wr == h) {
                #pragma unroll
                for (int mt = 0; mt < 4; ++mt)
                    #pragma unroll
                    for (int nt = 0; nt < 4; ++nt)
                        #pragma unroll
                        for (int j = 0; j < 4; ++j) {
                            int m_l = mt * 16 + g * 4 + j;
                            int n_l = wc * 64 + nt * 16 + l15;
                            ep[m_l * 132 + n_l] = acc[mt][nt][j] * scale;
                        }
            }
            __syncthreads();
            #pragma unroll
            for (int rr = 0; rr < 4; ++rr) {
                int m_l = rr * 16 + (tid >> 4);
                int nc  = (tid & 15) * 8;
                ushort u[8];
                #pragma unroll
                for (int e = 0; e < 8; ++e) u[e] = f2bf(ep[m_l * 132 + nc + e]);
                int m_g = bm * 128 + h * 64 + m_l;
                int b = m_g >> 11, s = m_g & 2047;
                int n_g = bn * 128 + nc;
                int hh = n_g >> 6, d = n_g & 63;
                *(uint4*)&outb[(((size_t)(b * 16 + hh)) * 2048 + s) * 64 + d] = *(const uint4*)u;
            }
        }
    }
}

// -------- final GEMM: out = A @ W^T + bias (fp32 out) --------
// R14: coalesced epilogue via LDS bounce (2x16B stores/thread/pass).
__global__ __launch_bounds__(256, 2) void gemm_fc(
    const ushort* __restrict__ A, const ushort* __restrict__ W,
    float* __restrict__ outf, const float* __restrict__ bias)
{
    __shared__ __align__(16) char smem[49152];
    const int tid = threadIdx.x;
    const int lane = tid & 63;
    const int wid  = tid >> 6;
    const int wr = wid >> 1, wc = wid & 1;
    const int l15 = lane & 15, g = lane >> 4;

    f32x4 acc[4][4];
    #pragma unroll
    for (int i = 0; i < 4; ++i)
        #pragma unroll
        for (int j = 0; j < 4; ++j) acc[i][j] = zero4();

    gemm_core<false>(A, W, smem, blockIdx.x, blockIdx.y, tid, acc);

    float* ep = (float*)smem;
    #pragma unroll
    for (int h = 0; h < 2; ++h) {
        __syncthreads();
        if (wr == h) {
            #pragma unroll
            for (int mt = 0; mt < 4; ++mt)
                #pragma unroll
                for (int nt = 0; nt < 4; ++nt)
                    #pragma unroll
                    for (int j = 0; j < 4; ++j) {
                        int m_l = mt * 16 + g * 4 + j;
                        int n_l = wc * 64 + nt * 16 + l15;
                        ep[m_l * 132 + n_l] = acc[mt][nt][j];
                    }
        }
        __syncthreads();
        #pragma unroll
        for (int rr = 0; rr < 4; ++rr) {
            int m_l = rr * 16 + (tid >> 4);
            int nc  = (tid & 15) * 8;
            int m_g = blockIdx.x * 128 + h * 64 + m_l;
            int n_g = blockIdx.y * 128 + nc;
            float4 v0, v1;
            v0.x = ep[m_l * 132 + nc + 0] + bias[n_g + 0];
            v0.y = ep[m_l * 132 + nc + 1] + bias[n_g + 1];
            v0.z = ep[m_l * 132 + nc + 2] + bias[n_g + 2];
            v0.w = ep[m_l * 132 + nc + 3] + bias[n_g + 3];
            v1.x = ep[m_l * 132 + nc + 4] + bias[n_g + 4];
            v1.y = ep[m_l * 132 + nc + 5] + bias[n_g + 5];
            v1.z = ep[m_l * 132 + nc + 6] + bias[n_g + 6];
            v1.w = ep[m_l * 132 + nc + 7] + bias[n_g + 7];
            *(float4*)&outf[(size_t)m_g * 1024 + n_g]     = v0;
            *(float4*)&outf[(size_t)m_g * 1024 + n_g + 4] = v1;
        }
    }
}

// -------- causal flash attention (R13 state — accepted) --------
// grid 512 1-D, block 512 = 8 waves. ONE q-tile per block.
// id mapping: blocks c and c+256 get qt and 15-qt -> CU pairs total 17 iters.
// __launch_bounds__(512, 2): arg2 empirically = min BLOCKS/CU (CUDA semantics)
// on this toolchain — (512,4)/(1024,*) clamp VGPR to 64 and spill.
__global__ __launch_bounds__(512, 2) void attn_kernel(
    const ushort* __restrict__ qh, const ushort* __restrict__ kh,
    const ushort* __restrict__ vhT, ushort* __restrict__ yb)
{
    __shared__ __align__(16) char smem[65536];
    const int tid = threadIdx.x;
    const int lane = tid & 63, wid = tid >> 6;
    const int l31 = lane & 31;
    const int hi  = lane >> 5;
    const int group = wid >> 2;          // 0 = even KV-64 half, 1 = odd
    const int wq    = wid & 3;
    const int subkv = group * 64;
    const int id = blockIdx.x;
    const int lo = id & 255;
    const int bh = (lo & 7) * 4 + ((lo >> 3) & 3);   // 4 heads per XCD slot-group
    const int qt = (id < 256) ? (lo >> 5) : 15 - (lo >> 5);
    const size_t base = (size_t)bh * 2048 * 64;
    const int b_ = bh >> 4, h_ = bh & 15;
    const int qrw = qt * 128 + wq * 32;
    float* oml = (float*)smem;

    auto stageK = [&](int t, int b) {
        char* Ks = smem + b * 32768;
        #pragma unroll
        for (int it = 0; it < 2; ++it) {
            int c = it * 512 + tid;
            int row = c >> 3, inner = c & 7;
            async16((const char*)kh + (base + (size_t)(t * 128 + row) * 64) * 2 + ((inner ^ (row & 7)) * 16),
                    Ks + c * 16);
        }
    };
    auto stageV = [&](int t, int b) {
        char* Vs = smem + b * 32768 + 16384;
        #pragma unroll
        for (int it = 0; it < 2; ++it) {
            int c = it * 512 + tid;
            int row = c >> 4, inner = c & 15;   // row = d
            async16((const char*)vhT + (base + (size_t)row * 2048 + (size_t)t * 128) * 2 + ((inner ^ (row & 15)) * 16),
                    Vs + c * 16);
        }
    };

    // hoist Q fragments (pre-scaled by 0.125*log2e at projection)
    bf16x8 qf[4];
    #pragma unroll
    for (int ks = 0; ks < 4; ++ks)
        qf[ks] = *(const bf16x8*)((const char*)qh + (base + (size_t)(qrw + l31) * 64) * 2 + ks * 32 + hi * 16);

    f32x16 o[2];
    #pragma unroll
    for (int r = 0; r < 16; ++r) { o[0][r] = 0.f; o[1][r] = 0.f; }
    float m_run = -1e30f, l_run = 0.f;

    stageK(0, 0); stageV(0, 0);

    for (int t = 0; t <= qt; ++t) {
        const bool more = (t + 1 <= qt);
        if (more) { stageK(t + 1, (t + 1) & 1); stageV(t + 1, (t + 1) & 1); }
        PIPE_BARRIER(more);

        const int kv0 = t * 128 + subkv;
        if (kv0 <= qrw + 31) {
            const char* Ks = smem + (t & 1) * 32768;
            const char* Vs = Ks + 16384;

            // ---- QK^T (swapped), K-fragments batched per-tt
            f32x16 st[2];
            #pragma unroll
            for (int r = 0; r < 16; ++r) { st[0][r] = 0.f; st[1][r] = 0.f; }
            #pragma unroll
            for (int tt = 0; tt < 2; ++tt) {
                bf16x8 kf[4];
                #pragma unroll
                for (int ks = 0; ks < 4; ++ks) {
                    int krow = subkv + tt * 32 + l31;
                    int byte = (krow * 128 + ks * 32 + hi * 16) ^ ((krow & 7) << 4);
                    kf[ks] = *(const bf16x8*)(Ks + byte);
                }
                __builtin_amdgcn_s_setprio(1);
                #pragma unroll
                for (int ks = 0; ks < 4; ++ks)
                    st[tt] = mfma32(kf[ks], qf[ks], st[tt]);
                __builtin_amdgcn_s_setprio(0);
            }

            // ---- hoist ALL V-fragment reads; softmax VALU below hides latency
            bf16x8 vf[4][2];
            #pragma unroll
            for (int ks = 0; ks < 4; ++ks)
                #pragma unroll
                for (int dt = 0; dt < 2; ++dt) {
                    int vrow = dt * 32 + l31;
                    int colB = subkv * 2 + ks * 32 + hi * 16;
                    int byte = vrow * 256 + (colB ^ ((vrow & 15) << 4));
                    vf[ks][dt] = *(const bf16x8*)(Vs + byte);
                }

            // ---- causal mask (diagonal tiles only)
            if (kv0 + 63 > qrw) {
                #pragma unroll
                for (int tt = 0; tt < 2; ++tt)
                    #pragma unroll
                    for (int r = 0; r < 16; ++r) {
                        int kv = kv0 + tt * 32 + (r & 3) + 8 * (r >> 2) + 4 * hi;
                        if (kv > qrw + l31) st[tt][r] = -1e30f;
                    }
            }

            // ---- row max: tree reduction + cross-half
            float mx;
            {
                float t0[8];
                #pragma unroll
                for (int r = 0; r < 8; ++r)
                    t0[r] = fmaxf(fmaxf(st[0][r], st[0][r + 8]),
                                  fmaxf(st[1][r], st[1][r + 8]));
                float t1[4];
                #pragma unroll
                for (int r = 0; r < 4; ++r) t1[r] = fmaxf(t0[r], t0[r + 4]);
                mx = fmaxf(fmaxf(t1[0], t1[2]), fmaxf(t1[1], t1[3]));
            }
            mx = xhalf_max(mx);

            // ---- defer-max online softmax (T13, THR=8 in log2 units)
            if (!__all(mx - m_run <= 8.0f)) {
                float mn = fmaxf(m_run, mx);
                float corr = __builtin_amdgcn_exp2f(m_run - mn);
                l_run *= corr;
                m_run = mn;
                #pragma unroll
                for (int r = 0; r < 16; ++r) {
                    int qsrc = (r & 3) + 8 * (r >> 2) + 4 * hi;
                    float c2 = __shfl(corr, qsrc);
                    o[0][r] *= c2; o[1][r] *= c2;
                }
            }

            // ---- exp2 + tree sum
            #pragma unroll
            for (int tt = 0; tt < 2; ++tt)
                #pragma unroll
                for (int r = 0; r < 16; ++r)
                    st[tt][r] = __builtin_amdgcn_exp2f(st[tt][r] - m_run);
            float sum;
            {
                float s0[8];
                #pragma unroll
                for (int r = 0; r < 8; ++r)
                    s0[r] = (st[0][r] + st[0][r + 8]) + (st[1][r] + st[1][r + 8]);
                float s1[4];
                #pragma unroll
                for (int r = 0; r < 4; ++r) s1[r] = s0[r] + s0[r + 4];
                sum = (s1[0] + s1[2]) + (s1[1] + s1[3]);
            }
            sum = xhalf_sum(sum);
            l_run += sum;

            // ---- pack P to bf16 words; exchange across halves (verified shfl_xor)
            unsigned Wd[2][8], Xw[2][8];
            #pragma unroll
            for (int tt = 0; tt < 2; ++tt)
                #pragma unroll
                for (int k = 0; k < 8; ++k) {
                    unsigned w;
                    asm("v_cvt_pk_bf16_f32 %0, %1, %2" : "=v"(w) : "v"(st[tt][2 * k]), "v"(st[tt][2 * k + 1]));
                    Wd[tt][k] = w;
                }
            #pragma unroll
            for (int tt = 0; tt < 2; ++tt)
                #pragma unroll
                for (int k = 0; k < 8; ++k)
                    Xw[tt][k] = __shfl_xor((int)Wd[tt][k], 32);

            // ---- PV (V already in registers)
            #pragma unroll
            for (int ks = 0; ks < 4; ++ks) {
                const int t2 = ks >> 1, bse = (ks & 1) * 4;
                unsigned w0 = hi ? Xw[t2][bse + 2] : Wd[t2][bse + 0];
                unsigned w1 = hi ? Xw[t2][bse + 3] : Wd[t2][bse + 1];
                unsigned w2 = hi ? Wd[t2][bse + 2] : Xw[t2][bse + 0];
                unsigned w3 = hi ? Wd[t2][bse + 3] : Xw[t2][bse + 1];
                unsigned pw4[4] = {w0, w1, w2, w3};
                bf16x8 pf = *(const bf16x8*)pw4;
                __builtin_amdgcn_s_setprio(1);
                #pragma unroll
                for (int dt = 0; dt < 2; ++dt)
                    o[dt] = mfma32(pf, vf[ks][dt], o[dt]);
                __builtin_amdgcn_s_setprio(0);
            }
        }
        END_BARRIER();
    }

    // ---- merge the two KV halves (oml aliased over dead bufs), store q-tile
    if (group == 1) {
        float* pp = oml + (size_t)(wq * 64 + lane) * 36;
        #pragma unroll
        for (int r = 0; r < 16; ++r) { pp[r] = o[0][r]; pp[16 + r] = o[1][r]; }
        pp[32] = m_run; pp[33] = l_run;
    }
    __syncthreads();
    if (group == 0) {
        const float* pp = oml + (size_t)(wq * 64 + lane) * 36;
        float m1 = pp[32], l1 = pp[33];
        float mn = fmaxf(m_run, m1);
        float a0 = __builtin_amdgcn_exp2f(m_run - mn);
        float a1 = __builtin_amdgcn_exp2f(m1 - mn);
        float lt = l_run * a0 + l1 * a1;
        float invl = 1.0f / lt;
        #pragma unroll
        for (int r = 0; r < 16; ++r) {
            int qsrc = (r & 3) + 8 * (r >> 2) + 4 * hi;
            float f0 = __shfl(a0, qsrc);
            float f1 = __shfl(a1, qsrc);
            float iv = __shfl(invl, qsrc);
            float v0 = (o[0][r] * f0 + pp[r] * f1) * iv;
            float v1 = (o[1][r] * f0 + pp[16 + r] * f1) * iv;
            int q = qrw + qsrc;
            size_t rowoff = ((size_t)(b_ * 2048 + q)) * 1024 + h_ * 64;
            yb[rowoff + l31]      = f2bf(v0);
            yb[rowoff + 32 + l31] = f2bf(v1);
        }
    }
}

extern "C" void kernel_launch(void* const* d_in, const int* in_sizes, int n_in,
                              void* d_out, int out_size, void* d_ws, size_t ws_size,
                              hipStream_t stream)
{
    const size_t MD = 4096ull * 1024;
    const size_t WD = 1024ull * 1024;
    ushort* ws  = (ushort*)d_ws;
    ushort* Qb  = ws;
    ushort* Kb  = Qb + MD;
    ushort* Vb  = Kb + MD;
    ushort* qhb = Vb + MD;
    ushort* khb = qhb + MD;
    ushort* vhT = khb + MD;
    ushort* WQb = vhT + MD;
    ushort* WKb = WQb + WD;
    ushort* WVb = WKb + WD;
    ushort* Wfb = WVb + WD;
    ushort* yb  = Qb;   // alias: Qb dead after QKV projection

    cvt7_kernel<<<dim3(4096, 7), 256, 0, stream>>>(
        (const float*)d_in[0], (const float*)d_in[1], (const float*)d_in[2],
        (const float*)d_in[3], (const float*)d_in[4], (const float*)d_in[5],
        (const float*)d_in[6],
        Qb, Kb, Vb, WQb, WKb, WVb, Wfb);

    gemm_qkv<<<dim3(96, 8), 256, 0, stream>>>(Qb, Kb, Vb, WQb, WKb, WVb, qhb, khb, vhT);
    attn_kernel<<<512, 512, 0, stream>>>(qhb, khb, vhT, yb);
    gemm_fc<<<dim3(32, 8), 256, 0, stream>>>(yb, Wfb, (float*)d_out, (const float*)d_in[7]);
}

// Round 15
// 106.173 us; speedup vs baseline: 1.0371x; 1.0371x over previous
//
#include <hip/hip_runtime.h>

typedef __attribute__((ext_vector_type(8))) short bf16x8;
typedef __attribute__((ext_vector_type(4))) float f32x4;
typedef __attribute__((ext_vector_type(16))) float f32x16;

__device__ __forceinline__ ushort f2bf(float f) {
    union { float f; unsigned u; } x; x.f = f;
    unsigned r = x.u + 0x7fffu + ((x.u >> 16) & 1u);
    return (ushort)(r >> 16);
}

__device__ __forceinline__ void async16(const void* g, void* l) {
    __builtin_amdgcn_global_load_lds(
        (const __attribute__((address_space(1))) void*)g,
        (__attribute__((address_space(3))) void*)l, 16, 0, 0);
}

__device__ __forceinline__ f32x4 mfma16(bf16x8 a, bf16x8 b, f32x4 c) {
    return __builtin_amdgcn_mfma_f32_16x16x32_bf16(a, b, c, 0, 0, 0);
}
__device__ __forceinline__ f32x16 mfma32(bf16x8 a, bf16x8 b, f32x16 c) {
    return __builtin_amdgcn_mfma_f32_32x32x16_bf16(a, b, c, 0, 0, 0);
}

__device__ __forceinline__ f32x4 zero4() { f32x4 z = {0.f, 0.f, 0.f, 0.f}; return z; }

// cross-half (lane vs lane^32) reduce — VERIFIED shfl_xor form (R3-R5/R8/R9).
// NOTE: inline-asm v_permlane32_swap_b32 failed correctness in both operand
// orders (R6/R7, absmax ~4) — do not reintroduce.
__device__ __forceinline__ float xhalf_max(float v) {
    return fmaxf(v, __shfl_xor(v, 32));
}
__device__ __forceinline__ float xhalf_sum(float v) {
    return v + __shfl_xor(v, 32);
}

// counted-vmcnt barriers. N = loads allowed to stay in flight (the next
// tile's prefetch). Protocol verified in attn (R8-R13) and gemm (R5-R13).
#define PIPE_BARRIER4(cond_more)                                         \
    do {                                                                 \
        if (cond_more) asm volatile("s_waitcnt vmcnt(4)" ::: "memory");  \
        else           asm volatile("s_waitcnt vmcnt(0)" ::: "memory");  \
        asm volatile("s_waitcnt lgkmcnt(0)" ::: "memory");               \
        __builtin_amdgcn_sched_barrier(0);                               \
        __builtin_amdgcn_s_barrier();                                    \
        __builtin_amdgcn_sched_barrier(0);                               \
    } while (0)

#define PIPE_BARRIER8(cond_more)                                         \
    do {                                                                 \
        if (cond_more) asm volatile("s_waitcnt vmcnt(8)" ::: "memory");  \
        else           asm volatile("s_waitcnt vmcnt(0)" ::: "memory");  \
        asm volatile("s_waitcnt lgkmcnt(0)" ::: "memory");               \
        __builtin_amdgcn_sched_barrier(0);                               \
        __builtin_amdgcn_s_barrier();                                    \
        __builtin_amdgcn_sched_barrier(0);                               \
    } while (0)

#define END_BARRIER()                                                    \
    do {                                                                 \
        asm volatile("s_waitcnt lgkmcnt(0)" ::: "memory");               \
        __builtin_amdgcn_sched_barrier(0);                               \
        __builtin_amdgcn_s_barrier();                                    \
        __builtin_amdgcn_sched_barrier(0);                               \
    } while (0)

// -------- fused fp32 -> bf16 conversion for all 7 tensors, one launch --------
__global__ void cvt7_kernel(
    const float* __restrict__ s0, const float* __restrict__ s1, const float* __restrict__ s2,
    const float* __restrict__ s3, const float* __restrict__ s4, const float* __restrict__ s5,
    const float* __restrict__ s6,
    ushort* __restrict__ d0, ushort* __restrict__ d1, ushort* __restrict__ d2,
    ushort* __restrict__ d3, ushort* __restrict__ d4, ushort* __restrict__ d5,
    ushort* __restrict__ d6)
{
    int y = blockIdx.y;
    const float* s; ushort* d; int n4;
    if      (y == 0) { s = s0; d = d0; n4 = 1048576; }
    else if (y == 1) { s = s1; d = d1; n4 = 1048576; }
    else if (y == 2) { s = s2; d = d2; n4 = 1048576; }
    else if (y == 3) { s = s3; d = d3; n4 = 262144; }
    else if (y == 4) { s = s4; d = d4; n4 = 262144; }
    else if (y == 5) { s = s5; d = d5; n4 = 262144; }
    else             { s = s6; d = d6; n4 = 262144; }
    int i = blockIdx.x * 256 + threadIdx.x;
    if (i >= n4) return;
    float4 v = ((const float4*)s)[i];
    ushort4 o;
    o.x = f2bf(v.x); o.y = f2bf(v.y); o.z = f2bf(v.z); o.w = f2bf(v.w);
    ((ushort4*)d)[i] = o;
}

// -------- shared GEMM core: 128x128 tile, BK=64 (R15), 2-deep counted-vmcnt --------
// 16 K-iters, 32 MFMA/wave per barrier pair (2x R13's amortization).
// LDS 64KB (2 bufs x (A 16KB + B 16KB)); layout/swizzle verified in R2-R4.
template<bool SWAP>
__device__ __forceinline__ void gemm_core(
    const ushort* __restrict__ A, const ushort* __restrict__ W,
    char* smem, int bm, int bn, int tid, f32x4 acc[4][4])
{
    const int lane = tid & 63;
    const int wid  = tid >> 6;
    const int wr = wid >> 1, wc = wid & 1;
    const int l15 = lane & 15, g = lane >> 4;

    auto stage = [&](int kt) {
        char* As = smem + (kt & 1) * 32768;
        char* Bs = As + 16384;
        #pragma unroll
        for (int it = 0; it < 4; ++it) {
            int c = it * 256 + tid;          // 16B chunk, 8 per 128B row
            int row = c >> 3, inner = c & 7;
            int srcoff = (inner ^ (row & 7)) * 16;
            async16((const char*)A + (size_t)(bm * 128 + row) * 2048 + kt * 128 + srcoff, As + c * 16);
            async16((const char*)W + (size_t)(bn * 128 + row) * 2048 + kt * 128 + srcoff, Bs + c * 16);
        }
    };

    stage(0);

    for (int kt = 0; kt < 16; ++kt) {
        const bool more = (kt < 15);
        if (more) stage(kt + 1);
        PIPE_BARRIER8(more);   // own stage(kt) landed; stage(kt+1)'s 8 stay in flight

        const char* As = smem + (kt & 1) * 32768;
        const char* Bs = As + 16384;
        bf16x8 af[4][2], bfr[4][2];
        #pragma unroll
        for (int mt = 0; mt < 4; ++mt)
            #pragma unroll
            for (int ks = 0; ks < 2; ++ks) {
                int row = wr * 64 + mt * 16 + l15;
                int byte = (row * 128 + ks * 64 + g * 16) ^ ((row & 7) << 4);
                af[mt][ks] = *(const bf16x8*)(As + byte);
            }
        #pragma unroll
        for (int nt = 0; nt < 4; ++nt)
            #pragma unroll
            for (int ks = 0; ks < 2; ++ks) {
                int row = wc * 64 + nt * 16 + l15;
                int byte = (row * 128 + ks * 64 + g * 16) ^ ((row & 7) << 4);
                bfr[nt][ks] = *(const bf16x8*)(Bs + byte);
            }
        __builtin_amdgcn_s_setprio(1);
        #pragma unroll
        for (int mt = 0; mt < 4; ++mt)
            #pragma unroll
            for (int nt = 0; nt < 4; ++nt)
                #pragma unroll
                for (int ks = 0; ks < 2; ++ks) {
                    if (SWAP) acc[mt][nt] = mfma16(bfr[nt][ks], af[mt][ks], acc[mt][nt]);
                    else      acc[mt][nt] = mfma16(af[mt][ks], bfr[nt][ks], acc[mt][nt]);
                }
        __builtin_amdgcn_s_setprio(0);
        END_BARRIER();   // all waves' reads of buf kt&1 done -> stage(kt+2) may overwrite
    }
}

// -------- merged QKV projection: grid (96, 8), z = x%3 --------
// Q scaled by 0.125*log2(e) (exp2-domain softmax downstream).
__global__ __launch_bounds__(256, 2) void gemm_qkv(
    const ushort* __restrict__ Qb, const ushort* __restrict__ Kb, const ushort* __restrict__ Vb,
    const ushort* __restrict__ WQ, const ushort* __restrict__ WK, const ushort* __restrict__ WV,
    ushort* __restrict__ qhb, ushort* __restrict__ khb, ushort* __restrict__ vhT)
{
    __shared__ __align__(16) char smem[65536];
    const int tid = threadIdx.x;
    const int z  = blockIdx.x % 3;
    const int bm = blockIdx.x / 3;
    const int bn = blockIdx.y;
    const int lane = tid & 63;
    const int wid  = tid >> 6;
    const int wr = wid >> 1, wc = wid & 1;
    const int l15 = lane & 15, g = lane >> 4;

    const ushort* A  = (z == 0) ? Qb : (z == 1) ? Kb : Vb;
    const ushort* Wm = (z == 0) ? WQ : (z == 1) ? WK : WV;

    f32x4 acc[4][4];
    #pragma unroll
    for (int i = 0; i < 4; ++i)
        #pragma unroll
        for (int j = 0; j < 4; ++j) acc[i][j] = zero4();

    if (z == 2) {
        gemm_core<true>(A, Wm, smem, bm, bn, tid, acc);
        #pragma unroll
        for (int mt = 0; mt < 4; ++mt)
            #pragma unroll
            for (int nt = 0; nt < 4; ++nt)
                #pragma unroll
                for (int j = 0; j < 4; ++j) {
                    int n = bn * 128 + wc * 64 + nt * 16 + g * 4 + j;
                    int m = bm * 128 + wr * 64 + mt * 16 + l15;
                    int b = m >> 11, s = m & 2047, h = (n >> 6) & 15, d = n & 63;
                    vhT[(((size_t)(b * 16 + h)) * 64 + d) * 2048 + s] = f2bf(acc[mt][nt][j]);
                }
    } else {
        gemm_core<false>(A, Wm, smem, bm, bn, tid, acc);
        const float scale = (z == 0) ? 0.18033688011112042f : 1.0f;  // 0.125 * log2(e)
        ushort* outb = (z == 0) ? qhb : khb;
        #pragma unroll
        for (int mt = 0; mt < 4; ++mt)
            #pragma unroll
            for (int nt = 0; nt < 4; ++nt)
                #pragma unroll
                for (int j = 0; j < 4; ++j) {
                    int m = bm * 128 + wr * 64 + mt * 16 + g * 4 + j;
                    int n = bn * 128 + wc * 64 + nt * 16 + l15;
                    int b = m >> 11, s = m & 2047, h = n >> 6, d = n & 63;
                    outb[(((size_t)(b * 16 + h)) * 2048 + s) * 64 + d] = f2bf(acc[mt][nt][j] * scale);
                }
    }
}

// -------- final GEMM: out = A @ W^T + bias (fp32 out) --------
__global__ __launch_bounds__(256, 2) void gemm_fc(
    const ushort* __restrict__ A, const ushort* __restrict__ W,
    float* __restrict__ outf, const float* __restrict__ bias)
{
    __shared__ __align__(16) char smem[65536];
    const int tid = threadIdx.x;
    const int lane = tid & 63;
    const int wid  = tid >> 6;
    const int wr = wid >> 1, wc = wid & 1;
    const int l15 = lane & 15, g = lane >> 4;

    f32x4 acc[4][4];
    #pragma unroll
    for (int i = 0; i < 4; ++i)
        #pragma unroll
        for (int j = 0; j < 4; ++j) acc[i][j] = zero4();

    gemm_core<false>(A, W, smem, blockIdx.x, blockIdx.y, tid, acc);

    #pragma unroll
    for (int mt = 0; mt < 4; ++mt)
        #pragma unroll
        for (int nt = 0; nt < 4; ++nt)
            #pragma unroll
            for (int j = 0; j < 4; ++j) {
                int m = blockIdx.x * 128 + wr * 64 + mt * 16 + g * 4 + j;
                int n = blockIdx.y * 128 + wc * 64 + nt * 16 + l15;
                outf[(size_t)m * 1024 + n] = acc[mt][nt][j] + bias[n];
            }
}

// -------- causal flash attention (R13 state — accepted) --------
// grid 512 1-D, block 512 = 8 waves. ONE q-tile per block.
// id mapping: blocks c and c+256 get qt and 15-qt -> CU pairs total 17 iters.
// __launch_bounds__(512, 2): arg2 empirically = min BLOCKS/CU (CUDA semantics)
// on this toolchain — (512,4)/(1024,*) clamp VGPR to 64 and spill.
__global__ __launch_bounds__(512, 2) void attn_kernel(
    const ushort* __restrict__ qh, const ushort* __restrict__ kh,
    const ushort* __restrict__ vhT, ushort* __restrict__ yb)
{
    __shared__ __align__(16) char smem[65536];
    const int tid = threadIdx.x;
    const int lane = tid & 63, wid = tid >> 6;
    const int l31 = lane & 31;
    const int hi  = lane >> 5;
    const int group = wid >> 2;          // 0 = even KV-64 half, 1 = odd
    const int wq    = wid & 3;
    const int subkv = group * 64;
    const int id = blockIdx.x;
    const int lo = id & 255;
    const int bh = (lo & 7) * 4 + ((lo >> 3) & 3);   // 4 heads per XCD slot-group
    const int qt = (id < 256) ? (lo >> 5) : 15 - (lo >> 5);
    const size_t base = (size_t)bh * 2048 * 64;
    const int b_ = bh >> 4, h_ = bh & 15;
    const int qrw = qt * 128 + wq * 32;
    float* oml = (float*)smem;

    auto stageK = [&](int t, int b) {
        char* Ks = smem + b * 32768;
        #pragma unroll
        for (int it = 0; it < 2; ++it) {
            int c = it * 512 + tid;
            int row = c >> 3, inner = c & 7;
            async16((const char*)kh + (base + (size_t)(t * 128 + row) * 64) * 2 + ((inner ^ (row & 7)) * 16),
                    Ks + c * 16);
        }
    };
    auto stageV = [&](int t, int b) {
        char* Vs = smem + b * 32768 + 16384;
        #pragma unroll
        for (int it = 0; it < 2; ++it) {
            int c = it * 512 + tid;
            int row = c >> 4, inner = c & 15;   // row = d
            async16((const char*)vhT + (base + (size_t)row * 2048 + (size_t)t * 128) * 2 + ((inner ^ (row & 15)) * 16),
                    Vs + c * 16);
        }
    };

    // hoist Q fragments (pre-scaled by 0.125*log2e at projection)
    bf16x8 qf[4];
    #pragma unroll
    for (int ks = 0; ks < 4; ++ks)
        qf[ks] = *(const bf16x8*)((const char*)qh + (base + (size_t)(qrw + l31) * 64) * 2 + ks * 32 + hi * 16);

    f32x16 o[2];
    #pragma unroll
    for (int r = 0; r < 16; ++r) { o[0][r] = 0.f; o[1][r] = 0.f; }
    float m_run = -1e30f, l_run = 0.f;

    stageK(0, 0); stageV(0, 0);

    for (int t = 0; t <= qt; ++t) {
        const bool more = (t + 1 <= qt);
        if (more) { stageK(t + 1, (t + 1) & 1); stageV(t + 1, (t + 1) & 1); }
        PIPE_BARRIER4(more);

        const int kv0 = t * 128 + subkv;
        if (kv0 <= qrw + 31) {
            const char* Ks = smem + (t & 1) * 32768;
            const char* Vs = Ks + 16384;

            // ---- QK^T (swapped), K-fragments batched per-tt
            f32x16 st[2];
            #pragma unroll
            for (int r = 0; r < 16; ++r) { st[0][r] = 0.f; st[1][r] = 0.f; }
            #pragma unroll
            for (int tt = 0; tt < 2; ++tt) {
                bf16x8 kf[4];
                #pragma unroll
                for (int ks = 0; ks < 4; ++ks) {
                    int krow = subkv + tt * 32 + l31;
                    int byte = (krow * 128 + ks * 32 + hi * 16) ^ ((krow & 7) << 4);
                    kf[ks] = *(const bf16x8*)(Ks + byte);
                }
                __builtin_amdgcn_s_setprio(1);
                #pragma unroll
                for (int ks = 0; ks < 4; ++ks)
                    st[tt] = mfma32(kf[ks], qf[ks], st[tt]);
                __builtin_amdgcn_s_setprio(0);
            }

            // ---- hoist ALL V-fragment reads; softmax VALU below hides latency
            bf16x8 vf[4][2];
            #pragma unroll
            for (int ks = 0; ks < 4; ++ks)
                #pragma unroll
                for (int dt = 0; dt < 2; ++dt) {
                    int vrow = dt * 32 + l31;
                    int colB = subkv * 2 + ks * 32 + hi * 16;
                    int byte = vrow * 256 + (colB ^ ((vrow & 15) << 4));
                    vf[ks][dt] = *(const bf16x8*)(Vs + byte);
                }

            // ---- causal mask (diagonal tiles only)
            if (kv0 + 63 > qrw) {
                #pragma unroll
                for (int tt = 0; tt < 2; ++tt)
                    #pragma unroll
                    for (int r = 0; r < 16; ++r) {
                        int kv = kv0 + tt * 32 + (r & 3) + 8 * (r >> 2) + 4 * hi;
                        if (kv > qrw + l31) st[tt][r] = -1e30f;
                    }
            }

            // ---- row max: tree reduction + cross-half
            float mx;
            {
                float t0[8];
                #pragma unroll
                for (int r = 0; r < 8; ++r)
                    t0[r] = fmaxf(fmaxf(st[0][r], st[0][r + 8]),
                                  fmaxf(st[1][r], st[1][r + 8]));
                float t1[4];
                #pragma unroll
                for (int r = 0; r < 4; ++r) t1[r] = fmaxf(t0[r], t0[r + 4]);
                mx = fmaxf(fmaxf(t1[0], t1[2]), fmaxf(t1[1], t1[3]));
            }
            mx = xhalf_max(mx);

            // ---- defer-max online softmax (T13, THR=8 in log2 units)
            if (!__all(mx - m_run <= 8.0f)) {
                float mn = fmaxf(m_run, mx);
                float corr = __builtin_amdgcn_exp2f(m_run - mn);
                l_run *= corr;
                m_run = mn;
                #pragma unroll
                for (int r = 0; r < 16; ++r) {
                    int qsrc = (r & 3) + 8 * (r >> 2) + 4 * hi;
                    float c2 = __shfl(corr, qsrc);
                    o[0][r] *= c2; o[1][r] *= c2;
                }
            }

            // ---- exp2 + tree sum
            #pragma unroll
            for (int tt = 0; tt < 2; ++tt)
                #pragma unroll
                for (int r = 0; r < 16; ++r)
                    st[tt][r] = __builtin_amdgcn_exp2f(st[tt][r] - m_run);
            float sum;
            {
                float s0[8];
                #pragma unroll
                for (int r = 0; r < 8; ++r)
                    s0[r] = (st[0][r] + st[0][r + 8]) + (st[1][r] + st[1][r + 8]);
                float s1[4];
                #pragma unroll
                for (int r = 0; r < 4; ++r) s1[r] = s0[r] + s0[r + 4];
                sum = (s1[0] + s1[2]) + (s1[1] + s1[3]);
            }
            sum = xhalf_sum(sum);
            l_run += sum;

            // ---- pack P to bf16 words; exchange across halves (verified shfl_xor)
            unsigned Wd[2][8], Xw[2][8];
            #pragma unroll
            for (int tt = 0; tt < 2; ++tt)
                #pragma unroll
                for (int k = 0; k < 8; ++k) {
                    unsigned w;
                    asm("v_cvt_pk_bf16_f32 %0, %1, %2" : "=v"(w) : "v"(st[tt][2 * k]), "v"(st[tt][2 * k + 1]));
                    Wd[tt][k] = w;
                }
            #pragma unroll
            for (int tt = 0; tt < 2; ++tt)
                #pragma unroll
                for (int k = 0; k < 8; ++k)
                    Xw[tt][k] = __shfl_xor((int)Wd[tt][k], 32);

            // ---- PV (V already in registers)
            #pragma unroll
            for (int ks = 0; ks < 4; ++ks) {
                const int t2 = ks >> 1, bse = (ks & 1) * 4;
                unsigned w0 = hi ? Xw[t2][bse + 2] : Wd[t2][bse + 0];
                unsigned w1 = hi ? Xw[t2][bse + 3] : Wd[t2][bse + 1];
                unsigned w2 = hi ? Wd[t2][bse + 2] : Xw[t2][bse + 0];
                unsigned w3 = hi ? Wd[t2][bse + 3] : Xw[t2][bse + 1];
                unsigned pw4[4] = {w0, w1, w2, w3};
                bf16x8 pf = *(const bf16x8*)pw4;
                __builtin_amdgcn_s_setprio(1);
                #pragma unroll
                for (int dt = 0; dt < 2; ++dt)
                    o[dt] = mfma32(pf, vf[ks][dt], o[dt]);
                __builtin_amdgcn_s_setprio(0);
            }
        }
        END_BARRIER();
    }

    // ---- merge the two KV halves (oml aliased over dead bufs), store q-tile
    if (group == 1) {
        float* pp = oml + (size_t)(wq * 64 + lane) * 36;
        #pragma unroll
        for (int r = 0; r < 16; ++r) { pp[r] = o[0][r]; pp[16 + r] = o[1][r]; }
        pp[32] = m_run; pp[33] = l_run;
    }
    __syncthreads();
    if (group == 0) {
        const float* pp = oml + (size_t)(wq * 64 + lane) * 36;
        float m1 = pp[32], l1 = pp[33];
        float mn = fmaxf(m_run, m1);
        float a0 = __builtin_amdgcn_exp2f(m_run - mn);
        float a1 = __builtin_amdgcn_exp2f(m1 - mn);
        float lt = l_run * a0 + l1 * a1;
        float invl = 1.0f / lt;
        #pragma unroll
        for (int r = 0; r < 16; ++r) {
            int qsrc = (r & 3) + 8 * (r >> 2) + 4 * hi;
            float f0 = __shfl(a0, qsrc);
            float f1 = __shfl(a1, qsrc);
            float iv = __shfl(invl, qsrc);
            float v0 = (o[0][r] * f0 + pp[r] * f1) * iv;
            float v1 = (o[1][r] * f0 + pp[16 + r] * f1) * iv;
            int q = qrw + qsrc;
            size_t rowoff = ((size_t)(b_ * 2048 + q)) * 1024 + h_ * 64;
            yb[rowoff + l31]      = f2bf(v0);
            yb[rowoff + 32 + l31] = f2bf(v1);
        }
    }
}

extern "C" void kernel_launch(void* const* d_in, const int* in_sizes, int n_in,
                              void* d_out, int out_size, void* d_ws, size_t ws_size,
                              hipStream_t stream)
{
    const size_t MD = 4096ull * 1024;
    const size_t WD = 1024ull * 1024;
    ushort* ws  = (ushort*)d_ws;
    ushort* Qb  = ws;
    ushort* Kb  = Qb + MD;
    ushort* Vb  = Kb + MD;
    ushort* qhb = Vb + MD;
    ushort* khb = qhb + MD;
    ushort* vhT = khb + MD;
    ushort* WQb = vhT + MD;
    ushort* WKb = WQb + WD;
    ushort* WVb = WKb + WD;
    ushort* Wfb = WVb + WD;
    ushort* yb  = Qb;   // alias: Qb dead after QKV projection

    cvt7_kernel<<<dim3(4096, 7), 256, 0, stream>>>(
        (const float*)d_in[0], (const float*)d_in[1], (const float*)d_in[2],
        (const float*)d_in[3], (const float*)d_in[4], (const float*)d_in[5],
        (const float*)d_in[6],
        Qb, Kb, Vb, WQb, WKb, WVb, Wfb);

    gemm_qkv<<<dim3(96, 8), 256, 0, stream>>>(Qb, Kb, Vb, WQb, WKb, WVb, qhb, khb, vhT);
    attn_kernel<<<512, 512, 0, stream>>>(qhb, khb, vhT, yb);
    gemm_fc<<<dim3(32, 8), 256, 0, stream>>>(yb, Wfb, (float*)d_out, (const float*)d_in[7]);
}

// Round 16
// 104.739 us; speedup vs baseline: 1.0513x; 1.0137x over previous
//
#include <hip/hip_runtime.h>

typedef __attribute__((ext_vector_type(8))) short bf16x8;
typedef __attribute__((ext_vector_type(4))) float f32x4;
typedef __attribute__((ext_vector_type(16))) float f32x16;

__device__ __forceinline__ ushort f2bf(float f) {
    union { float f; unsigned u; } x; x.f = f;
    unsigned r = x.u + 0x7fffu + ((x.u >> 16) & 1u);
    return (ushort)(r >> 16);
}

__device__ __forceinline__ void async16(const void* g, void* l) {
    __builtin_amdgcn_global_load_lds(
        (const __attribute__((address_space(1))) void*)g,
        (__attribute__((address_space(3))) void*)l, 16, 0, 0);
}

__device__ __forceinline__ f32x4 mfma16(bf16x8 a, bf16x8 b, f32x4 c) {
    return __builtin_amdgcn_mfma_f32_16x16x32_bf16(a, b, c, 0, 0, 0);
}
__device__ __forceinline__ f32x16 mfma32(bf16x8 a, bf16x8 b, f32x16 c) {
    return __builtin_amdgcn_mfma_f32_32x32x16_bf16(a, b, c, 0, 0, 0);
}

__device__ __forceinline__ f32x4 zero4() { f32x4 z = {0.f, 0.f, 0.f, 0.f}; return z; }

__device__ __forceinline__ unsigned cvtpk(float lo, float hi) {
    unsigned w;
    asm("v_cvt_pk_bf16_f32 %0, %1, %2" : "=v"(w) : "v"(lo), "v"(hi));
    return w;
}

// cross-half (lane vs lane^32) reduce — VERIFIED shfl_xor form (R3-R5/R8/R9).
// NOTE: inline-asm v_permlane32_swap_b32 failed correctness in both operand
// orders (R6/R7, absmax ~4) — do not reintroduce.
__device__ __forceinline__ float xhalf_max(float v) {
    return fmaxf(v, __shfl_xor(v, 32));
}
__device__ __forceinline__ float xhalf_sum(float v) {
    return v + __shfl_xor(v, 32);
}

// counted-vmcnt barriers. N = loads allowed to stay in flight.
#define PIPE_BARRIER_N(N, cond_more)                                        \
    do {                                                                    \
        if (cond_more) asm volatile("s_waitcnt vmcnt(" #N ")" ::: "memory");\
        else           asm volatile("s_waitcnt vmcnt(0)" ::: "memory");     \
        asm volatile("s_waitcnt lgkmcnt(0)" ::: "memory");                  \
        __builtin_amdgcn_sched_barrier(0);                                  \
        __builtin_amdgcn_s_barrier();                                       \
        __builtin_amdgcn_sched_barrier(0);                                  \
    } while (0)

#define END_BARRIER()                                                    \
    do {                                                                 \
        asm volatile("s_waitcnt lgkmcnt(0)" ::: "memory");               \
        __builtin_amdgcn_sched_barrier(0);                               \
        __builtin_amdgcn_s_barrier();                                    \
        __builtin_amdgcn_sched_barrier(0);                               \
    } while (0)

// -------- fp32 -> bf16 conversion for the 4 weight tensors only (R16) --------
__global__ void cvt4_kernel(
    const float* __restrict__ s0, const float* __restrict__ s1,
    const float* __restrict__ s2, const float* __restrict__ s3,
    ushort* __restrict__ d0, ushort* __restrict__ d1,
    ushort* __restrict__ d2, ushort* __restrict__ d3)
{
    int y = blockIdx.y;
    const float* s; ushort* d;
    if      (y == 0) { s = s0; d = d0; }
    else if (y == 1) { s = s1; d = d1; }
    else if (y == 2) { s = s2; d = d2; }
    else             { s = s3; d = d3; }
    int i = blockIdx.x * 256 + threadIdx.x;   // 262144 float4s per tensor
    float4 v = ((const float4*)s)[i];
    ushort4 o;
    o.x = f2bf(v.x); o.y = f2bf(v.y); o.z = f2bf(v.z); o.w = f2bf(v.w);
    ((ushort4*)d)[i] = o;
}

// -------- fused-A GEMM core (R16): A is fp32, converted during staging --------
// 128x128 tile, BK=64, 2-deep. Per iter: issue 8 fp32 A-loads + 4 B-async16,
// barrier (vmcnt 12), compute, then cvt+ds_write A (loads hidden under MFMA),
// end barrier. LDS image identical to the async16 layout.
template<bool SWAP>
__device__ __forceinline__ void gemm_core_f32a(
    const float* __restrict__ A32, const ushort* __restrict__ W,
    char* smem, int bm, int bn, int tid, f32x4 acc[4][4])
{
    const int lane = tid & 63;
    const int wid  = tid >> 6;
    const int wr = wid >> 1, wc = wid & 1;
    const int l15 = lane & 15, g = lane >> 4;

    // per-chunk geometry (4 chunks/thread)
    int rowc[4], eoffc[4];
    #pragma unroll
    for (int it = 0; it < 4; ++it) {
        int c = it * 256 + tid;
        rowc[it]  = c >> 3;
        eoffc[it] = ((c & 7) ^ (rowc[it] & 7)) * 8;   // element offset in row
    }

    auto loadA = [&](int kt, float4 r[4][2]) {
        #pragma unroll
        for (int it = 0; it < 4; ++it) {
            const float* p = A32 + (size_t)(bm * 128 + rowc[it]) * 1024 + kt * 64 + eoffc[it];
            r[it][0] = *(const float4*)p;
            r[it][1] = *(const float4*)(p + 4);
        }
    };
    auto stageB = [&](int kt) {
        char* Bs = smem + (kt & 1) * 32768 + 16384;
        #pragma unroll
        for (int it = 0; it < 4; ++it) {
            int c = it * 256 + tid;
            int row = c >> 3, inner = c & 7;
            int srcoff = (inner ^ (row & 7)) * 16;
            async16((const char*)W + (size_t)(bn * 128 + row) * 2048 + kt * 128 + srcoff,
                    smem + (kt & 1) * 32768 + 16384 + c * 16);
            (void)Bs;
        }
    };
    auto writeA = [&](int kt, const float4 r[4][2]) {
        char* As = smem + (kt & 1) * 32768;
        #pragma unroll
        for (int it = 0; it < 4; ++it) {
            int c = it * 256 + tid;
            unsigned w[4];
            w[0] = cvtpk(r[it][0].x, r[it][0].y);
            w[1] = cvtpk(r[it][0].z, r[it][0].w);
            w[2] = cvtpk(r[it][1].x, r[it][1].y);
            w[3] = cvtpk(r[it][1].z, r[it][1].w);
            *(bf16x8*)(As + c * 16) = *(const bf16x8*)w;
        }
    };

    // prologue: fully stage tile 0 (one exposed A-load latency)
    {
        float4 r0[4][2];
        loadA(0, r0);
        stageB(0);
        writeA(0, r0);
    }

    for (int kt = 0; kt < 16; ++kt) {
        const bool more = (kt < 15);
        float4 rn[4][2];
        if (more) { loadA(kt + 1, rn); stageB(kt + 1); }
        // buf kt ready: B(kt) async16 landed (only A-loads(kt+1)+B(kt+1)=12 newer
        // may stay in flight); own A ds_writes drained via lgkm; barrier syncs waves.
        PIPE_BARRIER_N(12, more);

        const char* As = smem + (kt & 1) * 32768;
        const char* Bs = As + 16384;
        bf16x8 af[4][2], bfr[4][2];
        #pragma unroll
        for (int mt = 0; mt < 4; ++mt)
            #pragma unroll
            for (int ks = 0; ks < 2; ++ks) {
                int row = wr * 64 + mt * 16 + l15;
                int byte = (row * 128 + ks * 64 + g * 16) ^ ((row & 7) << 4);
                af[mt][ks] = *(const bf16x8*)(As + byte);
            }
        #pragma unroll
        for (int nt = 0; nt < 4; ++nt)
            #pragma unroll
            for (int ks = 0; ks < 2; ++ks) {
                int row = wc * 64 + nt * 16 + l15;
                int byte = (row * 128 + ks * 64 + g * 16) ^ ((row & 7) << 4);
                bfr[nt][ks] = *(const bf16x8*)(Bs + byte);
            }
        __builtin_amdgcn_s_setprio(1);
        #pragma unroll
        for (int mt = 0; mt < 4; ++mt)
            #pragma unroll
            for (int nt = 0; nt < 4; ++nt)
                #pragma unroll
                for (int ks = 0; ks < 2; ++ks) {
                    if (SWAP) acc[mt][nt] = mfma16(bfr[nt][ks], af[mt][ks], acc[mt][nt]);
                    else      acc[mt][nt] = mfma16(af[mt][ks], bfr[nt][ks], acc[mt][nt]);
                }
        __builtin_amdgcn_s_setprio(0);

        // A(kt+1) ds_write AFTER compute: the 8 loads had the MFMA block to land.
        // Safe: writes buf[(kt+1)&1]'s A region; all reads of that buffer
        // completed before END_BARRIER of iter kt-1.
        if (more) writeA(kt + 1, rn);

        END_BARRIER();   // reads of buf[kt&1] done -> next iter may overwrite
    }
}

// -------- plain-bf16 GEMM core (R15 state) for gemm_fc --------
template<bool SWAP>
__device__ __forceinline__ void gemm_core(
    const ushort* __restrict__ A, const ushort* __restrict__ W,
    char* smem, int bm, int bn, int tid, f32x4 acc[4][4])
{
    const int lane = tid & 63;
    const int wid  = tid >> 6;
    const int wr = wid >> 1, wc = wid & 1;
    const int l15 = lane & 15, g = lane >> 4;

    auto stage = [&](int kt) {
        char* As = smem + (kt & 1) * 32768;
        char* Bs = As + 16384;
        #pragma unroll
        for (int it = 0; it < 4; ++it) {
            int c = it * 256 + tid;
            int row = c >> 3, inner = c & 7;
            int srcoff = (inner ^ (row & 7)) * 16;
            async16((const char*)A + (size_t)(bm * 128 + row) * 2048 + kt * 128 + srcoff, As + c * 16);
            async16((const char*)W + (size_t)(bn * 128 + row) * 2048 + kt * 128 + srcoff, Bs + c * 16);
        }
    };

    stage(0);

    for (int kt = 0; kt < 16; ++kt) {
        const bool more = (kt < 15);
        if (more) stage(kt + 1);
        PIPE_BARRIER_N(8, more);

        const char* As = smem + (kt & 1) * 32768;
        const char* Bs = As + 16384;
        bf16x8 af[4][2], bfr[4][2];
        #pragma unroll
        for (int mt = 0; mt < 4; ++mt)
            #pragma unroll
            for (int ks = 0; ks < 2; ++ks) {
                int row = wr * 64 + mt * 16 + l15;
                int byte = (row * 128 + ks * 64 + g * 16) ^ ((row & 7) << 4);
                af[mt][ks] = *(const bf16x8*)(As + byte);
            }
        #pragma unroll
        for (int nt = 0; nt < 4; ++nt)
            #pragma unroll
            for (int ks = 0; ks < 2; ++ks) {
                int row = wc * 64 + nt * 16 + l15;
                int byte = (row * 128 + ks * 64 + g * 16) ^ ((row & 7) << 4);
                bfr[nt][ks] = *(const bf16x8*)(Bs + byte);
            }
        __builtin_amdgcn_s_setprio(1);
        #pragma unroll
        for (int mt = 0; mt < 4; ++mt)
            #pragma unroll
            for (int nt = 0; nt < 4; ++nt)
                #pragma unroll
                for (int ks = 0; ks < 2; ++ks) {
                    if (SWAP) acc[mt][nt] = mfma16(bfr[nt][ks], af[mt][ks], acc[mt][nt]);
                    else      acc[mt][nt] = mfma16(af[mt][ks], bfr[nt][ks], acc[mt][nt]);
                }
        __builtin_amdgcn_s_setprio(0);
        END_BARRIER();
    }
}

// -------- merged QKV projection: grid (96, 8), z = x%3; A read as fp32 (R16) --------
// Q scaled by 0.125*log2(e) (exp2-domain softmax downstream).
__global__ __launch_bounds__(256, 2) void gemm_qkv(
    const float* __restrict__ Q32, const float* __restrict__ K32, const float* __restrict__ V32,
    const ushort* __restrict__ WQ, const ushort* __restrict__ WK, const ushort* __restrict__ WV,
    ushort* __restrict__ qhb, ushort* __restrict__ khb, ushort* __restrict__ vhT)
{
    __shared__ __align__(16) char smem[65536];
    const int tid = threadIdx.x;
    const int z  = blockIdx.x % 3;
    const int bm = blockIdx.x / 3;
    const int bn = blockIdx.y;
    const int lane = tid & 63;
    const int wid  = tid >> 6;
    const int wr = wid >> 1, wc = wid & 1;
    const int l15 = lane & 15, g = lane >> 4;

    const float*  A  = (z == 0) ? Q32 : (z == 1) ? K32 : V32;
    const ushort* Wm = (z == 0) ? WQ : (z == 1) ? WK : WV;

    f32x4 acc[4][4];
    #pragma unroll
    for (int i = 0; i < 4; ++i)
        #pragma unroll
        for (int j = 0; j < 4; ++j) acc[i][j] = zero4();

    if (z == 2) {
        gemm_core_f32a<true>(A, Wm, smem, bm, bn, tid, acc);
        #pragma unroll
        for (int mt = 0; mt < 4; ++mt)
            #pragma unroll
            for (int nt = 0; nt < 4; ++nt)
                #pragma unroll
                for (int j = 0; j < 4; ++j) {
                    int n = bn * 128 + wc * 64 + nt * 16 + g * 4 + j;
                    int m = bm * 128 + wr * 64 + mt * 16 + l15;
                    int b = m >> 11, s = m & 2047, h = (n >> 6) & 15, d = n & 63;
                    vhT[(((size_t)(b * 16 + h)) * 64 + d) * 2048 + s] = f2bf(acc[mt][nt][j]);
                }
    } else {
        gemm_core_f32a<false>(A, Wm, smem, bm, bn, tid, acc);
        const float scale = (z == 0) ? 0.18033688011112042f : 1.0f;  // 0.125 * log2(e)
        ushort* outb = (z == 0) ? qhb : khb;
        #pragma unroll
        for (int mt = 0; mt < 4; ++mt)
            #pragma unroll
            for (int nt = 0; nt < 4; ++nt)
                #pragma unroll
                for (int j = 0; j < 4; ++j) {
                    int m = bm * 128 + wr * 64 + mt * 16 + g * 4 + j;
                    int n = bn * 128 + wc * 64 + nt * 16 + l15;
                    int b = m >> 11, s = m & 2047, h = n >> 6, d = n & 63;
                    outb[(((size_t)(b * 16 + h)) * 2048 + s) * 64 + d] = f2bf(acc[mt][nt][j] * scale);
                }
    }
}

// -------- final GEMM: out = A @ W^T + bias (fp32 out) --------
__global__ __launch_bounds__(256, 2) void gemm_fc(
    const ushort* __restrict__ A, const ushort* __restrict__ W,
    float* __restrict__ outf, const float* __restrict__ bias)
{
    __shared__ __align__(16) char smem[65536];
    const int tid = threadIdx.x;
    const int lane = tid & 63;
    const int wid  = tid >> 6;
    const int wr = wid >> 1, wc = wid & 1;
    const int l15 = lane & 15, g = lane >> 4;

    f32x4 acc[4][4];
    #pragma unroll
    for (int i = 0; i < 4; ++i)
        #pragma unroll
        for (int j = 0; j < 4; ++j) acc[i][j] = zero4();

    gemm_core<false>(A, W, smem, blockIdx.x, blockIdx.y, tid, acc);

    #pragma unroll
    for (int mt = 0; mt < 4; ++mt)
        #pragma unroll
        for (int nt = 0; nt < 4; ++nt)
            #pragma unroll
            for (int j = 0; j < 4; ++j) {
                int m = blockIdx.x * 128 + wr * 64 + mt * 16 + g * 4 + j;
                int n = blockIdx.y * 128 + wc * 64 + nt * 16 + l15;
                outf[(size_t)m * 1024 + n] = acc[mt][nt][j] + bias[n];
            }
}

// -------- causal flash attention (R13 state — accepted) --------
// grid 512 1-D, block 512 = 8 waves. ONE q-tile per block.
// id mapping: blocks c and c+256 get qt and 15-qt -> CU pairs total 17 iters.
// __launch_bounds__(512, 2): arg2 empirically = min BLOCKS/CU (CUDA semantics)
// on this toolchain — (512,4)/(1024,*) clamp VGPR to 64 and spill.
__global__ __launch_bounds__(512, 2) void attn_kernel(
    const ushort* __restrict__ qh, const ushort* __restrict__ kh,
    const ushort* __restrict__ vhT, ushort* __restrict__ yb)
{
    __shared__ __align__(16) char smem[65536];
    const int tid = threadIdx.x;
    const int lane = tid & 63, wid = tid >> 6;
    const int l31 = lane & 31;
    const int hi  = lane >> 5;
    const int group = wid >> 2;          // 0 = even KV-64 half, 1 = odd
    const int wq    = wid & 3;
    const int subkv = group * 64;
    const int id = blockIdx.x;
    const int lo = id & 255;
    const int bh = (lo & 7) * 4 + ((lo >> 3) & 3);   // 4 heads per XCD slot-group
    const int qt = (id < 256) ? (lo >> 5) : 15 - (lo >> 5);
    const size_t base = (size_t)bh * 2048 * 64;
    const int b_ = bh >> 4, h_ = bh & 15;
    const int qrw = qt * 128 + wq * 32;
    float* oml = (float*)smem;

    auto stageK = [&](int t, int b) {
        char* Ks = smem + b * 32768;
        #pragma unroll
        for (int it = 0; it < 2; ++it) {
            int c = it * 512 + tid;
            int row = c >> 3, inner = c & 7;
            async16((const char*)kh + (base + (size_t)(t * 128 + row) * 64) * 2 + ((inner ^ (row & 7)) * 16),
                    Ks + c * 16);
        }
    };
    auto stageV = [&](int t, int b) {
        char* Vs = smem + b * 32768 + 16384;
        #pragma unroll
        for (int it = 0; it < 2; ++it) {
            int c = it * 512 + tid;
            int row = c >> 4, inner = c & 15;   // row = d
            async16((const char*)vhT + (base + (size_t)row * 2048 + (size_t)t * 128) * 2 + ((inner ^ (row & 15)) * 16),
                    Vs + c * 16);
        }
    };

    // hoist Q fragments (pre-scaled by 0.125*log2e at projection)
    bf16x8 qf[4];
    #pragma unroll
    for (int ks = 0; ks < 4; ++ks)
        qf[ks] = *(const bf16x8*)((const char*)qh + (base + (size_t)(qrw + l31) * 64) * 2 + ks * 32 + hi * 16);

    f32x16 o[2];
    #pragma unroll
    for (int r = 0; r < 16; ++r) { o[0][r] = 0.f; o[1][r] = 0.f; }
    float m_run = -1e30f, l_run = 0.f;

    stageK(0, 0); stageV(0, 0);

    for (int t = 0; t <= qt; ++t) {
        const bool more = (t + 1 <= qt);
        if (more) { stageK(t + 1, (t + 1) & 1); stageV(t + 1, (t + 1) & 1); }
        PIPE_BARRIER_N(4, more);

        const int kv0 = t * 128 + subkv;
        if (kv0 <= qrw + 31) {
            const char* Ks = smem + (t & 1) * 32768;
            const char* Vs = Ks + 16384;

            // ---- QK^T (swapped), K-fragments batched per-tt
            f32x16 st[2];
            #pragma unroll
            for (int r = 0; r < 16; ++r) { st[0][r] = 0.f; st[1][r] = 0.f; }
            #pragma unroll
            for (int tt = 0; tt < 2; ++tt) {
                bf16x8 kf[4];
                #pragma unroll
                for (int ks = 0; ks < 4; ++ks) {
                    int krow = subkv + tt * 32 + l31;
                    int byte = (krow * 128 + ks * 32 + hi * 16) ^ ((krow & 7) << 4);
                    kf[ks] = *(const bf16x8*)(Ks + byte);
                }
                __builtin_amdgcn_s_setprio(1);
                #pragma unroll
                for (int ks = 0; ks < 4; ++ks)
                    st[tt] = mfma32(kf[ks], qf[ks], st[tt]);
                __builtin_amdgcn_s_setprio(0);
            }

            // ---- hoist ALL V-fragment reads; softmax VALU below hides latency
            bf16x8 vf[4][2];
            #pragma unroll
            for (int ks = 0; ks < 4; ++ks)
                #pragma unroll
                for (int dt = 0; dt < 2; ++dt) {
                    int vrow = dt * 32 + l31;
                    int colB = subkv * 2 + ks * 32 + hi * 16;
                    int byte = vrow * 256 + (colB ^ ((vrow & 15) << 4));
                    vf[ks][dt] = *(const bf16x8*)(Vs + byte);
                }

            // ---- causal mask (diagonal tiles only)
            if (kv0 + 63 > qrw) {
                #pragma unroll
                for (int tt = 0; tt < 2; ++tt)
                    #pragma unroll
                    for (int r = 0; r < 16; ++r) {
                        int kv = kv0 + tt * 32 + (r & 3) + 8 * (r >> 2) + 4 * hi;
                        if (kv > qrw + l31) st[tt][r] = -1e30f;
                    }
            }

            // ---- row max: tree reduction + cross-half
            float mx;
            {
                float t0[8];
                #pragma unroll
                for (int r = 0; r < 8; ++r)
                    t0[r] = fmaxf(fmaxf(st[0][r], st[0][r + 8]),
                                  fmaxf(st[1][r], st[1][r + 8]));
                float t1[4];
                #pragma unroll
                for (int r = 0; r < 4; ++r) t1[r] = fmaxf(t0[r], t0[r + 4]);
                mx = fmaxf(fmaxf(t1[0], t1[2]), fmaxf(t1[1], t1[3]));
            }
            mx = xhalf_max(mx);

            // ---- defer-max online softmax (T13, THR=8 in log2 units)
            if (!__all(mx - m_run <= 8.0f)) {
                float mn = fmaxf(m_run, mx);
                float corr = __builtin_amdgcn_exp2f(m_run - mn);
                l_run *= corr;
                m_run = mn;
                #pragma unroll
                for (int r = 0; r < 16; ++r) {
                    int qsrc = (r & 3) + 8 * (r >> 2) + 4 * hi;
                    float c2 = __shfl(corr, qsrc);
                    o[0][r] *= c2; o[1][r] *= c2;
                }
            }

            // ---- exp2 + tree sum
            #pragma unroll
            for (int tt = 0; tt < 2; ++tt)
                #pragma unroll
                for (int r = 0; r < 16; ++r)
                    st[tt][r] = __builtin_amdgcn_exp2f(st[tt][r] - m_run);
            float sum;
            {
                float s0[8];
                #pragma unroll
                for (int r = 0; r < 8; ++r)
                    s0[r] = (st[0][r] + st[0][r + 8]) + (st[1][r] + st[1][r + 8]);
                float s1[4];
                #pragma unroll
                for (int r = 0; r < 4; ++r) s1[r] = s0[r] + s0[r + 4];
                sum = (s1[0] + s1[2]) + (s1[1] + s1[3]);
            }
            sum = xhalf_sum(sum);
            l_run += sum;

            // ---- pack P to bf16 words; exchange across halves (verified shfl_xor)
            unsigned Wd[2][8], Xw[2][8];
            #pragma unroll
            for (int tt = 0; tt < 2; ++tt)
                #pragma unroll
                for (int k = 0; k < 8; ++k)
                    Wd[tt][k] = cvtpk(st[tt][2 * k], st[tt][2 * k + 1]);
            #pragma unroll
            for (int tt = 0; tt < 2; ++tt)
                #pragma unroll
                for (int k = 0; k < 8; ++k)
                    Xw[tt][k] = __shfl_xor((int)Wd[tt][k], 32);

            // ---- PV (V already in registers)
            #pragma unroll
            for (int ks = 0; ks < 4; ++ks) {
                const int t2 = ks >> 1, bse = (ks & 1) * 4;
                unsigned w0 = hi ? Xw[t2][bse + 2] : Wd[t2][bse + 0];
                unsigned w1 = hi ? Xw[t2][bse + 3] : Wd[t2][bse + 1];
                unsigned w2 = hi ? Wd[t2][bse + 2] : Xw[t2][bse + 0];
                unsigned w3 = hi ? Wd[t2][bse + 3] : Xw[t2][bse + 1];
                unsigned pw4[4] = {w0, w1, w2, w3};
                bf16x8 pf = *(const bf16x8*)pw4;
                __builtin_amdgcn_s_setprio(1);
                #pragma unroll
                for (int dt = 0; dt < 2; ++dt)
                    o[dt] = mfma32(pf, vf[ks][dt], o[dt]);
                __builtin_amdgcn_s_setprio(0);
            }
        }
        END_BARRIER();
    }

    // ---- merge the two KV halves (oml aliased over dead bufs), store q-tile
    if (group == 1) {
        float* pp = oml + (size_t)(wq * 64 + lane) * 36;
        #pragma unroll
        for (int r = 0; r < 16; ++r) { pp[r] = o[0][r]; pp[16 + r] = o[1][r]; }
        pp[32] = m_run; pp[33] = l_run;
    }
    __syncthreads();
    if (group == 0) {
        const float* pp = oml + (size_t)(wq * 64 + lane) * 36;
        float m1 = pp[32], l1 = pp[33];
        float mn = fmaxf(m_run, m1);
        float a0 = __builtin_amdgcn_exp2f(m_run - mn);
        float a1 = __builtin_amdgcn_exp2f(m1 - mn);
        float lt = l_run * a0 + l1 * a1;
        float invl = 1.0f / lt;
        #pragma unroll
        for (int r = 0; r < 16; ++r) {
            int qsrc = (r & 3) + 8 * (r >> 2) + 4 * hi;
            float f0 = __shfl(a0, qsrc);
            float f1 = __shfl(a1, qsrc);
            float iv = __shfl(invl, qsrc);
            float v0 = (o[0][r] * f0 + pp[r] * f1) * iv;
            float v1 = (o[1][r] * f0 + pp[16 + r] * f1) * iv;
            int q = qrw + qsrc;
            size_t rowoff = ((size_t)(b_ * 2048 + q)) * 1024 + h_ * 64;
            yb[rowoff + l31]      = f2bf(v0);
            yb[rowoff + 32 + l31] = f2bf(v1);
        }
    }
}

extern "C" void kernel_launch(void* const* d_in, const int* in_sizes, int n_in,
                              void* d_out, int out_size, void* d_ws, size_t ws_size,
                              hipStream_t stream)
{
    const size_t MD = 4096ull * 1024;
    const size_t WD = 1024ull * 1024;
    ushort* ws  = (ushort*)d_ws;
    ushort* Qb  = ws;          // (slot reused only as yb now)
    ushort* Kb  = Qb + MD;     // unused (kept for layout stability)
    ushort* Vb  = Kb + MD;     // unused
    ushort* qhb = Vb + MD;
    ushort* khb = qhb + MD;
    ushort* vhT = khb + MD;
    ushort* WQb = vhT + MD;
    ushort* WKb = WQb + WD;
    ushort* WVb = WKb + WD;
    ushort* Wfb = WVb + WD;
    ushort* yb  = Qb;

    cvt4_kernel<<<dim3(1024, 4), 256, 0, stream>>>(
        (const float*)d_in[3], (const float*)d_in[4], (const float*)d_in[5],
        (const float*)d_in[6],
        WQb, WKb, WVb, Wfb);

    gemm_qkv<<<dim3(96, 8), 256, 0, stream>>>(
        (const float*)d_in[0], (const float*)d_in[1], (const float*)d_in[2],
        WQb, WKb, WVb, qhb, khb, vhT);
    attn_kernel<<<512, 512, 0, stream>>>(qhb, khb, vhT, yb);
    gemm_fc<<<dim3(32, 8), 256, 0, stream>>>(yb, Wfb, (float*)d_out, (const float*)d_in[7]);
}

// Round 17
// 103.363 us; speedup vs baseline: 1.0653x; 1.0133x over previous
//
#include <hip/hip_runtime.h>

typedef __attribute__((ext_vector_type(8))) short bf16x8;
typedef __attribute__((ext_vector_type(4))) float f32x4;
typedef __attribute__((ext_vector_type(16))) float f32x16;

__device__ __forceinline__ ushort f2bf(float f) {
    union { float f; unsigned u; } x; x.f = f;
    unsigned r = x.u + 0x7fffu + ((x.u >> 16) & 1u);
    return (ushort)(r >> 16);
}

__device__ __forceinline__ void async16(const void* g, void* l) {
    __builtin_amdgcn_global_load_lds(
        (const __attribute__((address_space(1))) void*)g,
        (__attribute__((address_space(3))) void*)l, 16, 0, 0);
}

__device__ __forceinline__ f32x4 mfma16(bf16x8 a, bf16x8 b, f32x4 c) {
    return __builtin_amdgcn_mfma_f32_16x16x32_bf16(a, b, c, 0, 0, 0);
}
__device__ __forceinline__ f32x16 mfma32(bf16x8 a, bf16x8 b, f32x16 c) {
    return __builtin_amdgcn_mfma_f32_32x32x16_bf16(a, b, c, 0, 0, 0);
}

__device__ __forceinline__ f32x4 zero4() { f32x4 z = {0.f, 0.f, 0.f, 0.f}; return z; }

__device__ __forceinline__ unsigned cvtpk(float lo, float hi) {
    unsigned w;
    asm("v_cvt_pk_bf16_f32 %0, %1, %2" : "=v"(w) : "v"(lo), "v"(hi));
    return w;
}

// cross-half (lane vs lane^32) reduce — VERIFIED shfl_xor form (R3-R5/R8/R9).
// NOTE: inline-asm v_permlane32_swap_b32 failed correctness in both operand
// orders (R6/R7, absmax ~4) — do not reintroduce.
__device__ __forceinline__ float xhalf_max(float v) {
    return fmaxf(v, __shfl_xor(v, 32));
}
__device__ __forceinline__ float xhalf_sum(float v) {
    return v + __shfl_xor(v, 32);
}

// counted-vmcnt barriers. N = loads allowed to stay in flight.
#define PIPE_BARRIER_N(N, cond_more)                                        \
    do {                                                                    \
        if (cond_more) asm volatile("s_waitcnt vmcnt(" #N ")" ::: "memory");\
        else           asm volatile("s_waitcnt vmcnt(0)" ::: "memory");     \
        asm volatile("s_waitcnt lgkmcnt(0)" ::: "memory");                  \
        __builtin_amdgcn_sched_barrier(0);                                  \
        __builtin_amdgcn_s_barrier();                                       \
        __builtin_amdgcn_sched_barrier(0);                                  \
    } while (0)

#define END_BARRIER()                                                    \
    do {                                                                 \
        asm volatile("s_waitcnt lgkmcnt(0)" ::: "memory");               \
        __builtin_amdgcn_sched_barrier(0);                               \
        __builtin_amdgcn_s_barrier();                                    \
        __builtin_amdgcn_sched_barrier(0);                               \
    } while (0)

// -------- fp32 -> bf16 conversion for the 4 weight tensors only --------
__global__ void cvt4_kernel(
    const float* __restrict__ s0, const float* __restrict__ s1,
    const float* __restrict__ s2, const float* __restrict__ s3,
    ushort* __restrict__ d0, ushort* __restrict__ d1,
    ushort* __restrict__ d2, ushort* __restrict__ d3)
{
    int y = blockIdx.y;
    const float* s; ushort* d;
    if      (y == 0) { s = s0; d = d0; }
    else if (y == 1) { s = s1; d = d1; }
    else if (y == 2) { s = s2; d = d2; }
    else             { s = s3; d = d3; }
    int i = blockIdx.x * 256 + threadIdx.x;   // 262144 float4s per tensor
    float4 v = ((const float4*)s)[i];
    ushort4 o;
    o.x = f2bf(v.x); o.y = f2bf(v.y); o.z = f2bf(v.z); o.w = f2bf(v.w);
    ((ushort4*)d)[i] = o;
}

// -------- fused-A GEMM core: A is fp32, converted during staging (R16) --------
template<bool SWAP>
__device__ __forceinline__ void gemm_core_f32a(
    const float* __restrict__ A32, const ushort* __restrict__ W,
    char* smem, int bm, int bn, int tid, f32x4 acc[4][4])
{
    const int lane = tid & 63;
    const int wid  = tid >> 6;
    const int wr = wid >> 1, wc = wid & 1;
    const int l15 = lane & 15, g = lane >> 4;

    int rowc[4], eoffc[4];
    #pragma unroll
    for (int it = 0; it < 4; ++it) {
        int c = it * 256 + tid;
        rowc[it]  = c >> 3;
        eoffc[it] = ((c & 7) ^ (rowc[it] & 7)) * 8;
    }

    auto loadA = [&](int kt, float4 r[4][2]) {
        #pragma unroll
        for (int it = 0; it < 4; ++it) {
            const float* p = A32 + (size_t)(bm * 128 + rowc[it]) * 1024 + kt * 64 + eoffc[it];
            r[it][0] = *(const float4*)p;
            r[it][1] = *(const float4*)(p + 4);
        }
    };
    auto stageB = [&](int kt) {
        #pragma unroll
        for (int it = 0; it < 4; ++it) {
            int c = it * 256 + tid;
            int row = c >> 3, inner = c & 7;
            int srcoff = (inner ^ (row & 7)) * 16;
            async16((const char*)W + (size_t)(bn * 128 + row) * 2048 + kt * 128 + srcoff,
                    smem + (kt & 1) * 32768 + 16384 + c * 16);
        }
    };
    auto writeA = [&](int kt, const float4 r[4][2]) {
        char* As = smem + (kt & 1) * 32768;
        #pragma unroll
        for (int it = 0; it < 4; ++it) {
            int c = it * 256 + tid;
            unsigned w[4];
            w[0] = cvtpk(r[it][0].x, r[it][0].y);
            w[1] = cvtpk(r[it][0].z, r[it][0].w);
            w[2] = cvtpk(r[it][1].x, r[it][1].y);
            w[3] = cvtpk(r[it][1].z, r[it][1].w);
            *(bf16x8*)(As + c * 16) = *(const bf16x8*)w;
        }
    };

    {
        float4 r0[4][2];
        loadA(0, r0);
        stageB(0);
        writeA(0, r0);
    }

    for (int kt = 0; kt < 16; ++kt) {
        const bool more = (kt < 15);
        float4 rn[4][2];
        if (more) { loadA(kt + 1, rn); stageB(kt + 1); }
        PIPE_BARRIER_N(12, more);

        const char* As = smem + (kt & 1) * 32768;
        const char* Bs = As + 16384;
        bf16x8 af[4][2], bfr[4][2];
        #pragma unroll
        for (int mt = 0; mt < 4; ++mt)
            #pragma unroll
            for (int ks = 0; ks < 2; ++ks) {
                int row = wr * 64 + mt * 16 + l15;
                int byte = (row * 128 + ks * 64 + g * 16) ^ ((row & 7) << 4);
                af[mt][ks] = *(const bf16x8*)(As + byte);
            }
        #pragma unroll
        for (int nt = 0; nt < 4; ++nt)
            #pragma unroll
            for (int ks = 0; ks < 2; ++ks) {
                int row = wc * 64 + nt * 16 + l15;
                int byte = (row * 128 + ks * 64 + g * 16) ^ ((row & 7) << 4);
                bfr[nt][ks] = *(const bf16x8*)(Bs + byte);
            }
        __builtin_amdgcn_s_setprio(1);
        #pragma unroll
        for (int mt = 0; mt < 4; ++mt)
            #pragma unroll
            for (int nt = 0; nt < 4; ++nt)
                #pragma unroll
                for (int ks = 0; ks < 2; ++ks) {
                    if (SWAP) acc[mt][nt] = mfma16(bfr[nt][ks], af[mt][ks], acc[mt][nt]);
                    else      acc[mt][nt] = mfma16(af[mt][ks], bfr[nt][ks], acc[mt][nt]);
                }
        __builtin_amdgcn_s_setprio(0);

        if (more) writeA(kt + 1, rn);

        END_BARRIER();
    }
}

// -------- plain-bf16 GEMM core (R15 state) for gemm_fc --------
template<bool SWAP>
__device__ __forceinline__ void gemm_core(
    const ushort* __restrict__ A, const ushort* __restrict__ W,
    char* smem, int bm, int bn, int tid, f32x4 acc[4][4])
{
    const int lane = tid & 63;
    const int wid  = tid >> 6;
    const int wr = wid >> 1, wc = wid & 1;
    const int l15 = lane & 15, g = lane >> 4;

    auto stage = [&](int kt) {
        char* As = smem + (kt & 1) * 32768;
        char* Bs = As + 16384;
        #pragma unroll
        for (int it = 0; it < 4; ++it) {
            int c = it * 256 + tid;
            int row = c >> 3, inner = c & 7;
            int srcoff = (inner ^ (row & 7)) * 16;
            async16((const char*)A + (size_t)(bm * 128 + row) * 2048 + kt * 128 + srcoff, As + c * 16);
            async16((const char*)W + (size_t)(bn * 128 + row) * 2048 + kt * 128 + srcoff, Bs + c * 16);
        }
    };

    stage(0);

    for (int kt = 0; kt < 16; ++kt) {
        const bool more = (kt < 15);
        if (more) stage(kt + 1);
        PIPE_BARRIER_N(8, more);

        const char* As = smem + (kt & 1) * 32768;
        const char* Bs = As + 16384;
        bf16x8 af[4][2], bfr[4][2];
        #pragma unroll
        for (int mt = 0; mt < 4; ++mt)
            #pragma unroll
            for (int ks = 0; ks < 2; ++ks) {
                int row = wr * 64 + mt * 16 + l15;
                int byte = (row * 128 + ks * 64 + g * 16) ^ ((row & 7) << 4);
                af[mt][ks] = *(const bf16x8*)(As + byte);
            }
        #pragma unroll
        for (int nt = 0; nt < 4; ++nt)
            #pragma unroll
            for (int ks = 0; ks < 2; ++ks) {
                int row = wc * 64 + nt * 16 + l15;
                int byte = (row * 128 + ks * 64 + g * 16) ^ ((row & 7) << 4);
                bfr[nt][ks] = *(const bf16x8*)(Bs + byte);
            }
        __builtin_amdgcn_s_setprio(1);
        #pragma unroll
        for (int mt = 0; mt < 4; ++mt)
            #pragma unroll
            for (int nt = 0; nt < 4; ++nt)
                #pragma unroll
                for (int ks = 0; ks < 2; ++ks) {
                    if (SWAP) acc[mt][nt] = mfma16(bfr[nt][ks], af[mt][ks], acc[mt][nt]);
                    else      acc[mt][nt] = mfma16(af[mt][ks], bfr[nt][ks], acc[mt][nt]);
                }
        __builtin_amdgcn_s_setprio(0);
        END_BARRIER();
    }
}

// -------- merged QKV projection: 1-D grid 768, XCD-affine decode (R17) --------
// The 8 bn-blocks sharing one A-tile land on ids congruent mod 8 -> same XCD
// (round-robin dispatch) -> A-tile fetched from HBM once, re-reads hit L2.
// zm = (id>>6)*8 + (id&7) in [0,96); bn = (id>>3)&7; z = zm%3; bm = zm/3.
__global__ __launch_bounds__(256, 2) void gemm_qkv(
    const float* __restrict__ Q32, const float* __restrict__ K32, const float* __restrict__ V32,
    const ushort* __restrict__ WQ, const ushort* __restrict__ WK, const ushort* __restrict__ WV,
    ushort* __restrict__ qhb, ushort* __restrict__ khb, ushort* __restrict__ vhT)
{
    __shared__ __align__(16) char smem[65536];
    const int tid = threadIdx.x;
    const int id = blockIdx.x;
    const int zm = (id >> 6) * 8 + (id & 7);
    const int bn = (id >> 3) & 7;
    const int z  = zm % 3;
    const int bm = zm / 3;
    const int lane = tid & 63;
    const int wid  = tid >> 6;
    const int wr = wid >> 1, wc = wid & 1;
    const int l15 = lane & 15, g = lane >> 4;

    const float*  A  = (z == 0) ? Q32 : (z == 1) ? K32 : V32;
    const ushort* Wm = (z == 0) ? WQ : (z == 1) ? WK : WV;

    f32x4 acc[4][4];
    #pragma unroll
    for (int i = 0; i < 4; ++i)
        #pragma unroll
        for (int j = 0; j < 4; ++j) acc[i][j] = zero4();

    if (z == 2) {
        gemm_core_f32a<true>(A, Wm, smem, bm, bn, tid, acc);
        #pragma unroll
        for (int mt = 0; mt < 4; ++mt)
            #pragma unroll
            for (int nt = 0; nt < 4; ++nt)
                #pragma unroll
                for (int j = 0; j < 4; ++j) {
                    int n = bn * 128 + wc * 64 + nt * 16 + g * 4 + j;
                    int m = bm * 128 + wr * 64 + mt * 16 + l15;
                    int b = m >> 11, s = m & 2047, h = (n >> 6) & 15, d = n & 63;
                    vhT[(((size_t)(b * 16 + h)) * 64 + d) * 2048 + s] = f2bf(acc[mt][nt][j]);
                }
    } else {
        gemm_core_f32a<false>(A, Wm, smem, bm, bn, tid, acc);
        const float scale = (z == 0) ? 0.18033688011112042f : 1.0f;  // 0.125 * log2(e)
        ushort* outb = (z == 0) ? qhb : khb;
        #pragma unroll
        for (int mt = 0; mt < 4; ++mt)
            #pragma unroll
            for (int nt = 0; nt < 4; ++nt)
                #pragma unroll
                for (int j = 0; j < 4; ++j) {
                    int m = bm * 128 + wr * 64 + mt * 16 + g * 4 + j;
                    int n = bn * 128 + wc * 64 + nt * 16 + l15;
                    int b = m >> 11, s = m & 2047, h = n >> 6, d = n & 63;
                    outb[(((size_t)(b * 16 + h)) * 2048 + s) * 64 + d] = f2bf(acc[mt][nt][j] * scale);
                }
    }
}

// -------- final GEMM: out = A @ W^T + bias (fp32 out) --------
__global__ __launch_bounds__(256, 2) void gemm_fc(
    const ushort* __restrict__ A, const ushort* __restrict__ W,
    float* __restrict__ outf, const float* __restrict__ bias)
{
    __shared__ __align__(16) char smem[65536];
    const int tid = threadIdx.x;
    const int lane = tid & 63;
    const int wid  = tid >> 6;
    const int wr = wid >> 1, wc = wid & 1;
    const int l15 = lane & 15, g = lane >> 4;

    f32x4 acc[4][4];
    #pragma unroll
    for (int i = 0; i < 4; ++i)
        #pragma unroll
        for (int j = 0; j < 4; ++j) acc[i][j] = zero4();

    gemm_core<false>(A, W, smem, blockIdx.x, blockIdx.y, tid, acc);

    #pragma unroll
    for (int mt = 0; mt < 4; ++mt)
        #pragma unroll
        for (int nt = 0; nt < 4; ++nt)
            #pragma unroll
            for (int j = 0; j < 4; ++j) {
                int m = blockIdx.x * 128 + wr * 64 + mt * 16 + g * 4 + j;
                int n = blockIdx.y * 128 + wc * 64 + nt * 16 + l15;
                outf[(size_t)m * 1024 + n] = acc[mt][nt][j] + bias[n];
            }
}

// -------- causal flash attention (R13 state — accepted) --------
__global__ __launch_bounds__(512, 2) void attn_kernel(
    const ushort* __restrict__ qh, const ushort* __restrict__ kh,
    const ushort* __restrict__ vhT, ushort* __restrict__ yb)
{
    __shared__ __align__(16) char smem[65536];
    const int tid = threadIdx.x;
    const int lane = tid & 63, wid = tid >> 6;
    const int l31 = lane & 31;
    const int hi  = lane >> 5;
    const int group = wid >> 2;          // 0 = even KV-64 half, 1 = odd
    const int wq    = wid & 3;
    const int subkv = group * 64;
    const int id = blockIdx.x;
    const int lo = id & 255;
    const int bh = (lo & 7) * 4 + ((lo >> 3) & 3);   // 4 heads per XCD slot-group
    const int qt = (id < 256) ? (lo >> 5) : 15 - (lo >> 5);
    const size_t base = (size_t)bh * 2048 * 64;
    const int b_ = bh >> 4, h_ = bh & 15;
    const int qrw = qt * 128 + wq * 32;
    float* oml = (float*)smem;

    auto stageK = [&](int t, int b) {
        char* Ks = smem + b * 32768;
        #pragma unroll
        for (int it = 0; it < 2; ++it) {
            int c = it * 512 + tid;
            int row = c >> 3, inner = c & 7;
            async16((const char*)kh + (base + (size_t)(t * 128 + row) * 64) * 2 + ((inner ^ (row & 7)) * 16),
                    Ks + c * 16);
        }
    };
    auto stageV = [&](int t, int b) {
        char* Vs = smem + b * 32768 + 16384;
        #pragma unroll
        for (int it = 0; it < 2; ++it) {
            int c = it * 512 + tid;
            int row = c >> 4, inner = c & 15;   // row = d
            async16((const char*)vhT + (base + (size_t)row * 2048 + (size_t)t * 128) * 2 + ((inner ^ (row & 15)) * 16),
                    Vs + c * 16);
        }
    };

    // hoist Q fragments (pre-scaled by 0.125*log2e at projection)
    bf16x8 qf[4];
    #pragma unroll
    for (int ks = 0; ks < 4; ++ks)
        qf[ks] = *(const bf16x8*)((const char*)qh + (base + (size_t)(qrw + l31) * 64) * 2 + ks * 32 + hi * 16);

    f32x16 o[2];
    #pragma unroll
    for (int r = 0; r < 16; ++r) { o[0][r] = 0.f; o[1][r] = 0.f; }
    float m_run = -1e30f, l_run = 0.f;

    stageK(0, 0); stageV(0, 0);

    for (int t = 0; t <= qt; ++t) {
        const bool more = (t + 1 <= qt);
        if (more) { stageK(t + 1, (t + 1) & 1); stageV(t + 1, (t + 1) & 1); }
        PIPE_BARRIER_N(4, more);

        const int kv0 = t * 128 + subkv;
        if (kv0 <= qrw + 31) {
            const char* Ks = smem + (t & 1) * 32768;
            const char* Vs = Ks + 16384;

            // ---- QK^T (swapped), K-fragments batched per-tt
            f32x16 st[2];
            #pragma unroll
            for (int r = 0; r < 16; ++r) { st[0][r] = 0.f; st[1][r] = 0.f; }
            #pragma unroll
            for (int tt = 0; tt < 2; ++tt) {
                bf16x8 kf[4];
                #pragma unroll
                for (int ks = 0; ks < 4; ++ks) {
                    int krow = subkv + tt * 32 + l31;
                    int byte = (krow * 128 + ks * 32 + hi * 16) ^ ((krow & 7) << 4);
                    kf[ks] = *(const bf16x8*)(Ks + byte);
                }
                __builtin_amdgcn_s_setprio(1);
                #pragma unroll
                for (int ks = 0; ks < 4; ++ks)
                    st[tt] = mfma32(kf[ks], qf[ks], st[tt]);
                __builtin_amdgcn_s_setprio(0);
            }

            // ---- hoist ALL V-fragment reads; softmax VALU below hides latency
            bf16x8 vf[4][2];
            #pragma unroll
            for (int ks = 0; ks < 4; ++ks)
                #pragma unroll
                for (int dt = 0; dt < 2; ++dt) {
                    int vrow = dt * 32 + l31;
                    int colB = subkv * 2 + ks * 32 + hi * 16;
                    int byte = vrow * 256 + (colB ^ ((vrow & 15) << 4));
                    vf[ks][dt] = *(const bf16x8*)(Vs + byte);
                }

            // ---- causal mask (diagonal tiles only)
            if (kv0 + 63 > qrw) {
                #pragma unroll
                for (int tt = 0; tt < 2; ++tt)
                    #pragma unroll
                    for (int r = 0; r < 16; ++r) {
                        int kv = kv0 + tt * 32 + (r & 3) + 8 * (r >> 2) + 4 * hi;
                        if (kv > qrw + l31) st[tt][r] = -1e30f;
                    }
            }

            // ---- row max: tree reduction + cross-half
            float mx;
            {
                float t0[8];
                #pragma unroll
                for (int r = 0; r < 8; ++r)
                    t0[r] = fmaxf(fmaxf(st[0][r], st[0][r + 8]),
                                  fmaxf(st[1][r], st[1][r + 8]));
                float t1[4];
                #pragma unroll
                for (int r = 0; r < 4; ++r) t1[r] = fmaxf(t0[r], t0[r + 4]);
                mx = fmaxf(fmaxf(t1[0], t1[2]), fmaxf(t1[1], t1[3]));
            }
            mx = xhalf_max(mx);

            // ---- defer-max online softmax (T13, THR=8 in log2 units)
            if (!__all(mx - m_run <= 8.0f)) {
                float mn = fmaxf(m_run, mx);
                float corr = __builtin_amdgcn_exp2f(m_run - mn);
                l_run *= corr;
                m_run = mn;
                #pragma unroll
                for (int r = 0; r < 16; ++r) {
                    int qsrc = (r & 3) + 8 * (r >> 2) + 4 * hi;
                    float c2 = __shfl(corr, qsrc);
                    o[0][r] *= c2; o[1][r] *= c2;
                }
            }

            // ---- exp2 + tree sum
            #pragma unroll
            for (int tt = 0; tt < 2; ++tt)
                #pragma unroll
                for (int r = 0; r < 16; ++r)
                    st[tt][r] = __builtin_amdgcn_exp2f(st[tt][r] - m_run);
            float sum;
            {
                float s0[8];
                #pragma unroll
                for (int r = 0; r < 8; ++r)
                    s0[r] = (st[0][r] + st[0][r + 8]) + (st[1][r] + st[1][r + 8]);
                float s1[4];
                #pragma unroll
                for (int r = 0; r < 4; ++r) s1[r] = s0[r] + s0[r + 4];
                sum = (s1[0] + s1[2]) + (s1[1] + s1[3]);
            }
            sum = xhalf_sum(sum);
            l_run += sum;

            // ---- pack P to bf16 words; exchange across halves (verified shfl_xor)
            unsigned Wd[2][8], Xw[2][8];
            #pragma unroll
            for (int tt = 0; tt < 2; ++tt)
                #pragma unroll
                for (int k = 0; k < 8; ++k)
                    Wd[tt][k] = cvtpk(st[tt][2 * k], st[tt][2 * k + 1]);
            #pragma unroll
            for (int tt = 0; tt < 2; ++tt)
                #pragma unroll
                for (int k = 0; k < 8; ++k)
                    Xw[tt][k] = __shfl_xor((int)Wd[tt][k], 32);

            // ---- PV (V already in registers)
            #pragma unroll
            for (int ks = 0; ks < 4; ++ks) {
                const int t2 = ks >> 1, bse = (ks & 1) * 4;
                unsigned w0 = hi ? Xw[t2][bse + 2] : Wd[t2][bse + 0];
                unsigned w1 = hi ? Xw[t2][bse + 3] : Wd[t2][bse + 1];
                unsigned w2 = hi ? Wd[t2][bse + 2] : Xw[t2][bse + 0];
                unsigned w3 = hi ? Wd[t2][bse + 3] : Xw[t2][bse + 1];
                unsigned pw4[4] = {w0, w1, w2, w3};
                bf16x8 pf = *(const bf16x8*)pw4;
                __builtin_amdgcn_s_setprio(1);
                #pragma unroll
                for (int dt = 0; dt < 2; ++dt)
                    o[dt] = mfma32(pf, vf[ks][dt], o[dt]);
                __builtin_amdgcn_s_setprio(0);
            }
        }
        END_BARRIER();
    }

    // ---- merge the two KV halves (oml aliased over dead bufs), store q-tile
    if (group == 1) {
        float* pp = oml + (size_t)(wq * 64 + lane) * 36;
        #pragma unroll
        for (int r = 0; r < 16; ++r) { pp[r] = o[0][r]; pp[16 + r] = o[1][r]; }
        pp[32] = m_run; pp[33] = l_run;
    }
    __syncthreads();
    if (group == 0) {
        const float* pp = oml + (size_t)(wq * 64 + lane) * 36;
        float m1 = pp[32], l1 = pp[33];
        float mn = fmaxf(m_run, m1);
        float a0 = __builtin_amdgcn_exp2f(m_run - mn);
        float a1 = __builtin_amdgcn_exp2f(m1 - mn);
        float lt = l_run * a0 + l1 * a1;
        float invl = 1.0f / lt;
        #pragma unroll
        for (int r = 0; r < 16; ++r) {
            int qsrc = (r & 3) + 8 * (r >> 2) + 4 * hi;
            float f0 = __shfl(a0, qsrc);
            float f1 = __shfl(a1, qsrc);
            float iv = __shfl(invl, qsrc);
            float v0 = (o[0][r] * f0 + pp[r] * f1) * iv;
            float v1 = (o[1][r] * f0 + pp[16 + r] * f1) * iv;
            int q = qrw + qsrc;
            size_t rowoff = ((size_t)(b_ * 2048 + q)) * 1024 + h_ * 64;
            yb[rowoff + l31]      = f2bf(v0);
            yb[rowoff + 32 + l31] = f2bf(v1);
        }
    }
}

extern "C" void kernel_launch(void* const* d_in, const int* in_sizes, int n_in,
                              void* d_out, int out_size, void* d_ws, size_t ws_size,
                              hipStream_t stream)
{
    const size_t MD = 4096ull * 1024;
    const size_t WD = 1024ull * 1024;
    ushort* ws  = (ushort*)d_ws;
    ushort* Qb  = ws;          // reused only as yb
    ushort* Kb  = Qb + MD;     // unused
    ushort* Vb  = Kb + MD;     // unused
    ushort* qhb = Vb + MD;
    ushort* khb = qhb + MD;
    ushort* vhT = khb + MD;
    ushort* WQb = vhT + MD;
    ushort* WKb = WQb + WD;
    ushort* WVb = WKb + WD;
    ushort* Wfb = WVb + WD;
    ushort* yb  = Qb;

    cvt4_kernel<<<dim3(1024, 4), 256, 0, stream>>>(
        (const float*)d_in[3], (const float*)d_in[4], (const float*)d_in[5],
        (const float*)d_in[6],
        WQb, WKb, WVb, Wfb);

    gemm_qkv<<<768, 256, 0, stream>>>(
        (const float*)d_in[0], (const float*)d_in[1], (const float*)d_in[2],
        WQb, WKb, WVb, qhb, khb, vhT);
    attn_kernel<<<512, 512, 0, stream>>>(qhb, khb, vhT, yb);
    gemm_fc<<<dim3(32, 8), 256, 0, stream>>>(yb, Wfb, (float*)d_out, (const float*)d_in[7]);
}

// Round 18
// 100.600 us; speedup vs baseline: 1.0946x; 1.0275x over previous
//
#include <hip/hip_runtime.h>

typedef __attribute__((ext_vector_type(8))) short bf16x8;
typedef __attribute__((ext_vector_type(4))) float f32x4;
typedef __attribute__((ext_vector_type(16))) float f32x16;

__device__ __forceinline__ ushort f2bf(float f) {
    union { float f; unsigned u; } x; x.f = f;
    unsigned r = x.u + 0x7fffu + ((x.u >> 16) & 1u);
    return (ushort)(r >> 16);
}

__device__ __forceinline__ void async16(const void* g, void* l) {
    __builtin_amdgcn_global_load_lds(
        (const __attribute__((address_space(1))) void*)g,
        (__attribute__((address_space(3))) void*)l, 16, 0, 0);
}

__device__ __forceinline__ f32x4 mfma16(bf16x8 a, bf16x8 b, f32x4 c) {
    return __builtin_amdgcn_mfma_f32_16x16x32_bf16(a, b, c, 0, 0, 0);
}
__device__ __forceinline__ f32x16 mfma32(bf16x8 a, bf16x8 b, f32x16 c) {
    return __builtin_amdgcn_mfma_f32_32x32x16_bf16(a, b, c, 0, 0, 0);
}

__device__ __forceinline__ f32x4 zero4() { f32x4 z = {0.f, 0.f, 0.f, 0.f}; return z; }

__device__ __forceinline__ unsigned cvtpk(float lo, float hi) {
    unsigned w;
    asm("v_cvt_pk_bf16_f32 %0, %1, %2" : "=v"(w) : "v"(lo), "v"(hi));
    return w;
}

// cross-half (lane vs lane^32) reduce — VERIFIED shfl_xor form (R3-R5/R8/R9).
// NOTE: inline-asm v_permlane32_swap_b32 failed correctness in both operand
// orders (R6/R7, absmax ~4) — do not reintroduce.
__device__ __forceinline__ float xhalf_max(float v) {
    return fmaxf(v, __shfl_xor(v, 32));
}
__device__ __forceinline__ float xhalf_sum(float v) {
    return v + __shfl_xor(v, 32);
}

// counted-vmcnt barriers. N = loads allowed to stay in flight.
#define PIPE_BARRIER_N(N, cond_more)                                        \
    do {                                                                    \
        if (cond_more) asm volatile("s_waitcnt vmcnt(" #N ")" ::: "memory");\
        else           asm volatile("s_waitcnt vmcnt(0)" ::: "memory");     \
        asm volatile("s_waitcnt lgkmcnt(0)" ::: "memory");                  \
        __builtin_amdgcn_sched_barrier(0);                                  \
        __builtin_amdgcn_s_barrier();                                       \
        __builtin_amdgcn_sched_barrier(0);                                  \
    } while (0)

#define END_BARRIER()                                                    \
    do {                                                                 \
        asm volatile("s_waitcnt lgkmcnt(0)" ::: "memory");               \
        __builtin_amdgcn_sched_barrier(0);                               \
        __builtin_amdgcn_s_barrier();                                    \
        __builtin_amdgcn_sched_barrier(0);                               \
    } while (0)

// -------- fp32 -> bf16 conversion for the 4 weight tensors only --------
__global__ void cvt4_kernel(
    const float* __restrict__ s0, const float* __restrict__ s1,
    const float* __restrict__ s2, const float* __restrict__ s3,
    ushort* __restrict__ d0, ushort* __restrict__ d1,
    ushort* __restrict__ d2, ushort* __restrict__ d3)
{
    int y = blockIdx.y;
    const float* s; ushort* d;
    if      (y == 0) { s = s0; d = d0; }
    else if (y == 1) { s = s1; d = d1; }
    else if (y == 2) { s = s2; d = d2; }
    else             { s = s3; d = d3; }
    int i = blockIdx.x * 256 + threadIdx.x;   // 262144 float4s per tensor
    float4 v = ((const float4*)s)[i];
    ushort4 o;
    o.x = f2bf(v.x); o.y = f2bf(v.y); o.z = f2bf(v.z); o.w = f2bf(v.w);
    ((ushort4*)d)[i] = o;
}

// -------- fused-A GEMM core: A fp32, converted during staging (R16) --------
// R18: 2-deep A-REGISTER pipeline — loadA(kt+2) issued at iter top, the slot
// loaded last iter is cvt+ds_written after compute. Each A-load gets ~2
// compute phases to land (compiler auto-waits the reg dependency).
template<bool SWAP>
__device__ __forceinline__ void gemm_core_f32a(
    const float* __restrict__ A32, const ushort* __restrict__ W,
    char* smem, int bm, int bn, int tid, f32x4 acc[4][4])
{
    const int lane = tid & 63;
    const int wid  = tid >> 6;
    const int wr = wid >> 1, wc = wid & 1;
    const int l15 = lane & 15, g = lane >> 4;

    int rowc[4], eoffc[4];
    #pragma unroll
    for (int it = 0; it < 4; ++it) {
        int c = it * 256 + tid;
        rowc[it]  = c >> 3;
        eoffc[it] = ((c & 7) ^ (rowc[it] & 7)) * 8;
    }

    auto loadA = [&](int kt, float4 r[4][2]) {
        #pragma unroll
        for (int it = 0; it < 4; ++it) {
            const float* p = A32 + (size_t)(bm * 128 + rowc[it]) * 1024 + kt * 64 + eoffc[it];
            r[it][0] = *(const float4*)p;
            r[it][1] = *(const float4*)(p + 4);
        }
    };
    auto stageB = [&](int kt) {
        #pragma unroll
        for (int it = 0; it < 4; ++it) {
            int c = it * 256 + tid;
            int row = c >> 3, inner = c & 7;
            int srcoff = (inner ^ (row & 7)) * 16;
            async16((const char*)W + (size_t)(bn * 128 + row) * 2048 + kt * 128 + srcoff,
                    smem + (kt & 1) * 32768 + 16384 + c * 16);
        }
    };
    auto writeA = [&](int kt, const float4 r[4][2]) {
        char* As = smem + (kt & 1) * 32768;
        #pragma unroll
        for (int it = 0; it < 4; ++it) {
            int c = it * 256 + tid;
            unsigned w[4];
            w[0] = cvtpk(r[it][0].x, r[it][0].y);
            w[1] = cvtpk(r[it][0].z, r[it][0].w);
            w[2] = cvtpk(r[it][1].x, r[it][1].y);
            w[3] = cvtpk(r[it][1].z, r[it][1].w);
            *(bf16x8*)(As + c * 16) = *(const bf16x8*)w;
        }
    };

    // Rotating 2-slot A-reg buffer (static indexing per rule #20: explicit
    // even/odd named slots, compile-time selected each unrolled iter).
    float4 raE[4][2], raO[4][2];

    // prologue: A(0) -> even slot, stage tile 0, A(1) -> odd slot
    loadA(0, raE);
    stageB(0);
    writeA(0, raE);
    loadA(1, raO);

    #pragma unroll 2
    for (int kt = 0; kt < 16; ++kt) {
        const bool more  = (kt < 15);
        const bool more2 = (kt < 14);
        if (more)  stageB(kt + 1);
        // issue A(kt+2) into the slot just freed by writeA(kt) / rotation
        if (more2) { if ((kt & 1) == 0) loadA(kt + 2, raE); else loadA(kt + 2, raO); }
        // B(kt) landed: newer loads allowed in flight = B(kt+1) 4 + A(kt+2) 8
        PIPE_BARRIER_N(12, more);

        const char* As = smem + (kt & 1) * 32768;
        const char* Bs = As + 16384;
        bf16x8 af[4][2], bfr[4][2];
        #pragma unroll
        for (int mt = 0; mt < 4; ++mt)
            #pragma unroll
            for (int ks = 0; ks < 2; ++ks) {
                int row = wr * 64 + mt * 16 + l15;
                int byte = (row * 128 + ks * 64 + g * 16) ^ ((row & 7) << 4);
                af[mt][ks] = *(const bf16x8*)(As + byte);
            }
        #pragma unroll
        for (int nt = 0; nt < 4; ++nt)
            #pragma unroll
            for (int ks = 0; ks < 2; ++ks) {
                int row = wc * 64 + nt * 16 + l15;
                int byte = (row * 128 + ks * 64 + g * 16) ^ ((row & 7) << 4);
                bfr[nt][ks] = *(const bf16x8*)(Bs + byte);
            }
        __builtin_amdgcn_s_setprio(1);
        #pragma unroll
        for (int mt = 0; mt < 4; ++mt)
            #pragma unroll
            for (int nt = 0; nt < 4; ++nt)
                #pragma unroll
                for (int ks = 0; ks < 2; ++ks) {
                    if (SWAP) acc[mt][nt] = mfma16(bfr[nt][ks], af[mt][ks], acc[mt][nt]);
                    else      acc[mt][nt] = mfma16(af[mt][ks], bfr[nt][ks], acc[mt][nt]);
                }
        __builtin_amdgcn_s_setprio(0);

        // A(kt+1) was loaded one full iter ago -> latency fully covered.
        if (more) { if ((kt & 1) == 0) writeA(kt + 1, raO); else writeA(kt + 1, raE); }

        END_BARRIER();   // reads of buf[kt&1] done -> next iter may overwrite
    }
}

// -------- plain-bf16 GEMM core (R15 state) for gemm_fc --------
template<bool SWAP>
__device__ __forceinline__ void gemm_core(
    const ushort* __restrict__ A, const ushort* __restrict__ W,
    char* smem, int bm, int bn, int tid, f32x4 acc[4][4])
{
    const int lane = tid & 63;
    const int wid  = tid >> 6;
    const int wr = wid >> 1, wc = wid & 1;
    const int l15 = lane & 15, g = lane >> 4;

    auto stage = [&](int kt) {
        char* As = smem + (kt & 1) * 32768;
        char* Bs = As + 16384;
        #pragma unroll
        for (int it = 0; it < 4; ++it) {
            int c = it * 256 + tid;
            int row = c >> 3, inner = c & 7;
            int srcoff = (inner ^ (row & 7)) * 16;
            async16((const char*)A + (size_t)(bm * 128 + row) * 2048 + kt * 128 + srcoff, As + c * 16);
            async16((const char*)W + (size_t)(bn * 128 + row) * 2048 + kt * 128 + srcoff, Bs + c * 16);
        }
    };

    stage(0);

    for (int kt = 0; kt < 16; ++kt) {
        const bool more = (kt < 15);
        if (more) stage(kt + 1);
        PIPE_BARRIER_N(8, more);

        const char* As = smem + (kt & 1) * 32768;
        const char* Bs = As + 16384;
        bf16x8 af[4][2], bfr[4][2];
        #pragma unroll
        for (int mt = 0; mt < 4; ++mt)
            #pragma unroll
            for (int ks = 0; ks < 2; ++ks) {
                int row = wr * 64 + mt * 16 + l15;
                int byte = (row * 128 + ks * 64 + g * 16) ^ ((row & 7) << 4);
                af[mt][ks] = *(const bf16x8*)(As + byte);
            }
        #pragma unroll
        for (int nt = 0; nt < 4; ++nt)
            #pragma unroll
            for (int ks = 0; ks < 2; ++ks) {
                int row = wc * 64 + nt * 16 + l15;
                int byte = (row * 128 + ks * 64 + g * 16) ^ ((row & 7) << 4);
                bfr[nt][ks] = *(const bf16x8*)(Bs + byte);
            }
        __builtin_amdgcn_s_setprio(1);
        #pragma unroll
        for (int mt = 0; mt < 4; ++mt)
            #pragma unroll
            for (int nt = 0; nt < 4; ++nt)
                #pragma unroll
                for (int ks = 0; ks < 2; ++ks) {
                    if (SWAP) acc[mt][nt] = mfma16(bfr[nt][ks], af[mt][ks], acc[mt][nt]);
                    else      acc[mt][nt] = mfma16(af[mt][ks], bfr[nt][ks], acc[mt][nt]);
                }
        __builtin_amdgcn_s_setprio(0);
        END_BARRIER();
    }
}

// -------- merged QKV projection: 1-D grid 768, XCD-affine decode (R17) --------
__global__ __launch_bounds__(256, 2) void gemm_qkv(
    const float* __restrict__ Q32, const float* __restrict__ K32, const float* __restrict__ V32,
    const ushort* __restrict__ WQ, const ushort* __restrict__ WK, const ushort* __restrict__ WV,
    ushort* __restrict__ qhb, ushort* __restrict__ khb, ushort* __restrict__ vhT)
{
    __shared__ __align__(16) char smem[65536];
    const int tid = threadIdx.x;
    const int id = blockIdx.x;
    const int zm = (id >> 6) * 8 + (id & 7);
    const int bn = (id >> 3) & 7;
    const int z  = zm % 3;
    const int bm = zm / 3;
    const int lane = tid & 63;
    const int wid  = tid >> 6;
    const int wr = wid >> 1, wc = wid & 1;
    const int l15 = lane & 15, g = lane >> 4;

    const float*  A  = (z == 0) ? Q32 : (z == 1) ? K32 : V32;
    const ushort* Wm = (z == 0) ? WQ : (z == 1) ? WK : WV;

    f32x4 acc[4][4];
    #pragma unroll
    for (int i = 0; i < 4; ++i)
        #pragma unroll
        for (int j = 0; j < 4; ++j) acc[i][j] = zero4();

    if (z == 2) {
        gemm_core_f32a<true>(A, Wm, smem, bm, bn, tid, acc);
        #pragma unroll
        for (int mt = 0; mt < 4; ++mt)
            #pragma unroll
            for (int nt = 0; nt < 4; ++nt)
                #pragma unroll
                for (int j = 0; j < 4; ++j) {
                    int n = bn * 128 + wc * 64 + nt * 16 + g * 4 + j;
                    int m = bm * 128 + wr * 64 + mt * 16 + l15;
                    int b = m >> 11, s = m & 2047, h = (n >> 6) & 15, d = n & 63;
                    vhT[(((size_t)(b * 16 + h)) * 64 + d) * 2048 + s] = f2bf(acc[mt][nt][j]);
                }
    } else {
        gemm_core_f32a<false>(A, Wm, smem, bm, bn, tid, acc);
        const float scale = (z == 0) ? 0.18033688011112042f : 1.0f;  // 0.125 * log2(e)
        ushort* outb = (z == 0) ? qhb : khb;
        #pragma unroll
        for (int mt = 0; mt < 4; ++mt)
            #pragma unroll
            for (int nt = 0; nt < 4; ++nt)
                #pragma unroll
                for (int j = 0; j < 4; ++j) {
                    int m = bm * 128 + wr * 64 + mt * 16 + g * 4 + j;
                    int n = bn * 128 + wc * 64 + nt * 16 + l15;
                    int b = m >> 11, s = m & 2047, h = n >> 6, d = n & 63;
                    outb[(((size_t)(b * 16 + h)) * 2048 + s) * 64 + d] = f2bf(acc[mt][nt][j] * scale);
                }
    }
}

// -------- final GEMM: out = A @ W^T + bias (fp32 out) --------
__global__ __launch_bounds__(256, 2) void gemm_fc(
    const ushort* __restrict__ A, const ushort* __restrict__ W,
    float* __restrict__ outf, const float* __restrict__ bias)
{
    __shared__ __align__(16) char smem[65536];
    const int tid = threadIdx.x;
    const int lane = tid & 63;
    const int wid  = tid >> 6;
    const int wr = wid >> 1, wc = wid & 1;
    const int l15 = lane & 15, g = lane >> 4;

    f32x4 acc[4][4];
    #pragma unroll
    for (int i = 0; i < 4; ++i)
        #pragma unroll
        for (int j = 0; j < 4; ++j) acc[i][j] = zero4();

    gemm_core<false>(A, W, smem, blockIdx.x, blockIdx.y, tid, acc);

    #pragma unroll
    for (int mt = 0; mt < 4; ++mt)
        #pragma unroll
        for (int nt = 0; nt < 4; ++nt)
            #pragma unroll
            for (int j = 0; j < 4; ++j) {
                int m = blockIdx.x * 128 + wr * 64 + mt * 16 + g * 4 + j;
                int n = blockIdx.y * 128 + wc * 64 + nt * 16 + l15;
                outf[(size_t)m * 1024 + n] = acc[mt][nt][j] + bias[n];
            }
}

// -------- causal flash attention (R13 state — accepted) --------
__global__ __launch_bounds__(512, 2) void attn_kernel(
    const ushort* __restrict__ qh, const ushort* __restrict__ kh,
    const ushort* __restrict__ vhT, ushort* __restrict__ yb)
{
    __shared__ __align__(16) char smem[65536];
    const int tid = threadIdx.x;
    const int lane = tid & 63, wid = tid >> 6;
    const int l31 = lane & 31;
    const int hi  = lane >> 5;
    const int group = wid >> 2;          // 0 = even KV-64 half, 1 = odd
    const int wq    = wid & 3;
    const int subkv = group * 64;
    const int id = blockIdx.x;
    const int lo = id & 255;
    const int bh = (lo & 7) * 4 + ((lo >> 3) & 3);   // 4 heads per XCD slot-group
    const int qt = (id < 256) ? (lo >> 5) : 15 - (lo >> 5);
    const size_t base = (size_t)bh * 2048 * 64;
    const int b_ = bh >> 4, h_ = bh & 15;
    const int qrw = qt * 128 + wq * 32;
    float* oml = (float*)smem;

    auto stageK = [&](int t, int b) {
        char* Ks = smem + b * 32768;
        #pragma unroll
        for (int it = 0; it < 2; ++it) {
            int c = it * 512 + tid;
            int row = c >> 3, inner = c & 7;
            async16((const char*)kh + (base + (size_t)(t * 128 + row) * 64) * 2 + ((inner ^ (row & 7)) * 16),
                    Ks + c * 16);
        }
    };
    auto stageV = [&](int t, int b) {
        char* Vs = smem + b * 32768 + 16384;
        #pragma unroll
        for (int it = 0; it < 2; ++it) {
            int c = it * 512 + tid;
            int row = c >> 4, inner = c & 15;   // row = d
            async16((const char*)vhT + (base + (size_t)row * 2048 + (size_t)t * 128) * 2 + ((inner ^ (row & 15)) * 16),
                    Vs + c * 16);
        }
    };

    // hoist Q fragments (pre-scaled by 0.125*log2e at projection)
    bf16x8 qf[4];
    #pragma unroll
    for (int ks = 0; ks < 4; ++ks)
        qf[ks] = *(const bf16x8*)((const char*)qh + (base + (size_t)(qrw + l31) * 64) * 2 + ks * 32 + hi * 16);

    f32x16 o[2];
    #pragma unroll
    for (int r = 0; r < 16; ++r) { o[0][r] = 0.f; o[1][r] = 0.f; }
    float m_run = -1e30f, l_run = 0.f;

    stageK(0, 0); stageV(0, 0);

    for (int t = 0; t <= qt; ++t) {
        const bool more = (t + 1 <= qt);
        if (more) { stageK(t + 1, (t + 1) & 1); stageV(t + 1, (t + 1) & 1); }
        PIPE_BARRIER_N(4, more);

        const int kv0 = t * 128 + subkv;
        if (kv0 <= qrw + 31) {
            const char* Ks = smem + (t & 1) * 32768;
            const char* Vs = Ks + 16384;

            // ---- QK^T (swapped), K-fragments batched per-tt
            f32x16 st[2];
            #pragma unroll
            for (int r = 0; r < 16; ++r) { st[0][r] = 0.f; st[1][r] = 0.f; }
            #pragma unroll
            for (int tt = 0; tt < 2; ++tt) {
                bf16x8 kf[4];
                #pragma unroll
                for (int ks = 0; ks < 4; ++ks) {
                    int krow = subkv + tt * 32 + l31;
                    int byte = (krow * 128 + ks * 32 + hi * 16) ^ ((krow & 7) << 4);
                    kf[ks] = *(const bf16x8*)(Ks + byte);
                }
                __builtin_amdgcn_s_setprio(1);
                #pragma unroll
                for (int ks = 0; ks < 4; ++ks)
                    st[tt] = mfma32(kf[ks], qf[ks], st[tt]);
                __builtin_amdgcn_s_setprio(0);
            }

            // ---- hoist ALL V-fragment reads; softmax VALU below hides latency
            bf16x8 vf[4][2];
            #pragma unroll
            for (int ks = 0; ks < 4; ++ks)
                #pragma unroll
                for (int dt = 0; dt < 2; ++dt) {
                    int vrow = dt * 32 + l31;
                    int colB = subkv * 2 + ks * 32 + hi * 16;
                    int byte = vrow * 256 + (colB ^ ((vrow & 15) << 4));
                    vf[ks][dt] = *(const bf16x8*)(Vs + byte);
                }

            // ---- causal mask (diagonal tiles only)
            if (kv0 + 63 > qrw) {
                #pragma unroll
                for (int tt = 0; tt < 2; ++tt)
                    #pragma unroll
                    for (int r = 0; r < 16; ++r) {
                        int kv = kv0 + tt * 32 + (r & 3) + 8 * (r >> 2) + 4 * hi;
                        if (kv > qrw + l31) st[tt][r] = -1e30f;
                    }
            }

            // ---- row max: tree reduction + cross-half
            float mx;
            {
                float t0[8];
                #pragma unroll
                for (int r = 0; r < 8; ++r)
                    t0[r] = fmaxf(fmaxf(st[0][r], st[0][r + 8]),
                                  fmaxf(st[1][r], st[1][r + 8]));
                float t1[4];
                #pragma unroll
                for (int r = 0; r < 4; ++r) t1[r] = fmaxf(t0[r], t0[r + 4]);
                mx = fmaxf(fmaxf(t1[0], t1[2]), fmaxf(t1[1], t1[3]));
            }
            mx = xhalf_max(mx);

            // ---- defer-max online softmax (T13, THR=8 in log2 units)
            if (!__all(mx - m_run <= 8.0f)) {
                float mn = fmaxf(m_run, mx);
                float corr = __builtin_amdgcn_exp2f(m_run - mn);
                l_run *= corr;
                m_run = mn;
                #pragma unroll
                for (int r = 0; r < 16; ++r) {
                    int qsrc = (r & 3) + 8 * (r >> 2) + 4 * hi;
                    float c2 = __shfl(corr, qsrc);
                    o[0][r] *= c2; o[1][r] *= c2;
                }
            }

            // ---- exp2 + tree sum
            #pragma unroll
            for (int tt = 0; tt < 2; ++tt)
                #pragma unroll
                for (int r = 0; r < 16; ++r)
                    st[tt][r] = __builtin_amdgcn_exp2f(st[tt][r] - m_run);
            float sum;
            {
                float s0[8];
                #pragma unroll
                for (int r = 0; r < 8; ++r)
                    s0[r] = (st[0][r] + st[0][r + 8]) + (st[1][r] + st[1][r + 8]);
                float s1[4];
                #pragma unroll
                for (int r = 0; r < 4; ++r) s1[r] = s0[r] + s0[r + 4];
                sum = (s1[0] + s1[2]) + (s1[1] + s1[3]);
            }
            sum = xhalf_sum(sum);
            l_run += sum;

            // ---- pack P to bf16 words; exchange across halves (verified shfl_xor)
            unsigned Wd[2][8], Xw[2][8];
            #pragma unroll
            for (int tt = 0; tt < 2; ++tt)
                #pragma unroll
                for (int k = 0; k < 8; ++k)
                    Wd[tt][k] = cvtpk(st[tt][2 * k], st[tt][2 * k + 1]);
            #pragma unroll
            for (int tt = 0; tt < 2; ++tt)
                #pragma unroll
                for (int k = 0; k < 8; ++k)
                    Xw[tt][k] = __shfl_xor((int)Wd[tt][k], 32);

            // ---- PV (V already in registers)
            #pragma unroll
            for (int ks = 0; ks < 4; ++ks) {
                const int t2 = ks >> 1, bse = (ks & 1) * 4;
                unsigned w0 = hi ? Xw[t2][bse + 2] : Wd[t2][bse + 0];
                unsigned w1 = hi ? Xw[t2][bse + 3] : Wd[t2][bse + 1];
                unsigned w2 = hi ? Wd[t2][bse + 2] : Xw[t2][bse + 0];
                unsigned w3 = hi ? Wd[t2][bse + 3] : Xw[t2][bse + 1];
                unsigned pw4[4] = {w0, w1, w2, w3};
                bf16x8 pf = *(const bf16x8*)pw4;
                __builtin_amdgcn_s_setprio(1);
                #pragma unroll
                for (int dt = 0; dt < 2; ++dt)
                    o[dt] = mfma32(pf, vf[ks][dt], o[dt]);
                __builtin_amdgcn_s_setprio(0);
            }
        }
        END_BARRIER();
    }

    // ---- merge the two KV halves (oml aliased over dead bufs), store q-tile
    if (group == 1) {
        float* pp = oml + (size_t)(wq * 64 + lane) * 36;
        #pragma unroll
        for (int r = 0; r < 16; ++r) { pp[r] = o[0][r]; pp[16 + r] = o[1][r]; }
        pp[32] = m_run; pp[33] = l_run;
    }
    __syncthreads();
    if (group == 0) {
        const float* pp = oml + (size_t)(wq * 64 + lane) * 36;
        float m1 = pp[32], l1 = pp[33];
        float mn = fmaxf(m_run, m1);
        float a0 = __builtin_amdgcn_exp2f(m_run - mn);
        float a1 = __builtin_amdgcn_exp2f(m1 - mn);
        float lt = l_run * a0 + l1 * a1;
        float invl = 1.0f / lt;
        #pragma unroll
        for (int r = 0; r < 16; ++r) {
            int qsrc = (r & 3) + 8 * (r >> 2) + 4 * hi;
            float f0 = __shfl(a0, qsrc);
            float f1 = __shfl(a1, qsrc);
            float iv = __shfl(invl, qsrc);
            float v0 = (o[0][r] * f0 + pp[r] * f1) * iv;
            float v1 = (o[1][r] * f0 + pp[16 + r] * f1) * iv;
            int q = qrw + qsrc;
            size_t rowoff = ((size_t)(b_ * 2048 + q)) * 1024 + h_ * 64;
            yb[rowoff + l31]      = f2bf(v0);
            yb[rowoff + 32 + l31] = f2bf(v1);
        }
    }
}

extern "C" void kernel_launch(void* const* d_in, const int* in_sizes, int n_in,
                              void* d_out, int out_size, void* d_ws, size_t ws_size,
                              hipStream_t stream)
{
    const size_t MD = 4096ull * 1024;
    const size_t WD = 1024ull * 1024;
    ushort* ws  = (ushort*)d_ws;
    ushort* Qb  = ws;          // reused only as yb
    ushort* Kb  = Qb + MD;     // unused
    ushort* Vb  = Kb + MD;     // unused
    ushort* qhb = Vb + MD;
    ushort* khb = qhb + MD;
    ushort* vhT = khb + MD;
    ushort* WQb = vhT + MD;
    ushort* WKb = WQb + WD;
    ushort* WVb = WKb + WD;
    ushort* Wfb = WVb + WD;
    ushort* yb  = Qb;

    cvt4_kernel<<<dim3(1024, 4), 256, 0, stream>>>(
        (const float*)d_in[3], (const float*)d_in[4], (const float*)d_in[5],
        (const float*)d_in[6],
        WQb, WKb, WVb, Wfb);

    gemm_qkv<<<768, 256, 0, stream>>>(
        (const float*)d_in[0], (const float*)d_in[1], (const float*)d_in[2],
        WQb, WKb, WVb, qhb, khb, vhT);
    attn_kernel<<<512, 512, 0, stream>>>(qhb, khb, vhT, yb);
    gemm_fc<<<dim3(32, 8), 256, 0, stream>>>(yb, Wfb, (float*)d_out, (const float*)d_in[7]);
}